// Round 15
// baseline (2310.918 us; speedup 1.0000x reference)
//
#include <hip/hip_runtime.h>
#include <hip/hip_bf16.h>

typedef __bf16 bf16_t;
typedef __bf16 bf16x8 __attribute__((ext_vector_type(8)));
typedef __bf16 bf16x4 __attribute__((ext_vector_type(4)));
typedef float  f32x4  __attribute__((ext_vector_type(4)));

#define DEV __device__ __forceinline__

DEV void gload_lds16(const void* g, void* l) {
  __builtin_amdgcn_global_load_lds(
      (__attribute__((address_space(1))) void*)(void*)g,
      (__attribute__((address_space(3))) void*)l, 16, 0, 0);
}

// ---------------- weight transpose+cast (batched over layers via z):
// in fp32 [L][K][N] -> out bf16 [L][N][K]. float4 reads, bf16x4 writes.
__global__ __launch_bounds__(256)
void transpose_cast(const float* __restrict__ in, bf16_t* __restrict__ out,
                    int K, int N) {
  __shared__ float tile[32][33];
  const long z = blockIdx.z;
  const float* inz = in + z * (long)K * N;
  bf16_t* outz = out + z * (long)N * K;
  const int k0 = blockIdx.x * 32;
  const int n0 = blockIdx.y * 32;
  const int tx = threadIdx.x & 7;        // n-chunk (x4)
  const int ty = threadIdx.x >> 3;       // 0..31
  const f32x4 ld = *(const f32x4*)&inz[(long)(k0 + ty) * N + n0 + tx * 4];
#pragma unroll
  for (int j = 0; j < 4; ++j) tile[ty][tx * 4 + j] = ld[j];
  __syncthreads();
  bf16x4 st;
#pragma unroll
  for (int j = 0; j < 4; ++j) st[j] = (bf16_t)tile[tx * 4 + j][ty];
  *(bf16x4*)&outz[(long)(n0 + ty) * K + k0 + tx * 4] = st;
}

// ---------------- embedding: h = wte[ids] + wpe[s]  (bf16 out, 8/thread)
__global__ __launch_bounds__(256)
void embed_kernel(const int* __restrict__ ids, const float* __restrict__ wte,
                  const float* __restrict__ wpe, bf16_t* __restrict__ h) {
  const int t = blockIdx.x * 256 + threadIdx.x;     // < 8192*96
  const int row = t / 96;
  const int c8  = (t % 96) * 8;
  const int s   = row & 1023;
  const float* wr = wte + (long)ids[row] * 768 + c8;
  const float* pr = wpe + (long)s * 768 + c8;
  bf16x8 o;
#pragma unroll
  for (int j = 0; j < 8; ++j) o[j] = (bf16_t)(wr[j] + pr[j]);
  *(bf16x8*)&h[(long)row * 768 + c8] = o;
}

// ---------------- layernorm: wave per row, 4 rows/block, vector loads,
// wave-only shfl reduction. x bf16; out bf16 (ob) or f32 (of).
template <bool BF16OUT>
__global__ __launch_bounds__(256)
void ln_kernel(const bf16_t* __restrict__ x, const float* __restrict__ g,
               const float* __restrict__ b, bf16_t* __restrict__ ob,
               float* __restrict__ of) {
  const int lane = threadIdx.x & 63;
  const long row = blockIdx.x * 4 + (threadIdx.x >> 6);
  const bf16_t* xr = x + row * 768;
  const bf16x8 v8 = *(const bf16x8*)&xr[lane * 8];          // cols [0,512)
  const bf16x4 v4 = *(const bf16x4*)&xr[512 + lane * 4];    // cols [512,768)
  float vv[12];
#pragma unroll
  for (int j = 0; j < 8; ++j) vv[j] = (float)v8[j];
#pragma unroll
  for (int j = 0; j < 4; ++j) vv[8 + j] = (float)v4[j];
  float s = 0.f, sq = 0.f;
#pragma unroll
  for (int j = 0; j < 12; ++j) { s += vv[j]; sq += vv[j] * vv[j]; }
#pragma unroll
  for (int o = 32; o; o >>= 1) { s += __shfl_xor(s, o); sq += __shfl_xor(sq, o); }
  const float mean = s * (1.f / 768.f);
  const float rs = rsqrtf(sq * (1.f / 768.f) - mean * mean + 1e-5f);
  if (BF16OUT) {
    bf16x8 o8; bf16x4 o4;
#pragma unroll
    for (int j = 0; j < 8; ++j) {
      const int col = lane * 8 + j;
      o8[j] = (bf16_t)((vv[j] - mean) * rs * g[col] + b[col]);
    }
#pragma unroll
    for (int j = 0; j < 4; ++j) {
      const int col = 512 + lane * 4 + j;
      o4[j] = (bf16_t)((vv[8 + j] - mean) * rs * g[col] + b[col]);
    }
    *(bf16x8*)&ob[row * 768 + lane * 8] = o8;
    *(bf16x4*)&ob[row * 768 + 512 + lane * 4] = o4;
  } else {
#pragma unroll
    for (int j = 0; j < 8; ++j) {
      const int col = lane * 8 + j;
      of[row * 768 + col] = (vv[j] - mean) * rs * g[col] + b[col];
    }
#pragma unroll
    for (int j = 0; j < 4; ++j) {
      const int col = 512 + lane * 4 + j;
      of[row * 768 + col] = (vv[8 + j] - mean) * rs * g[col] + b[col];
    }
  }
}

// ---------------- narrow GEMM (ao/op): BM=128, BN=64, BK=64, 256 thr.
// A-operand DIRECT from global (K-contig bf16x8 frags; A-tile 16KB -> L1;
// each row shared by only 2 waves) -> only B staged in LDS (8 KB, single
// buffer). Removes 2/3 of the gload bytes behind each barrier drain.
// EPI: 1 = bf16 residual RMW, 2 = bf16 store, 3 = gelu->bf16.
template <int EPI>
__global__ __launch_bounds__(256, 4)
void gemm_bt(const bf16_t* __restrict__ A, const bf16_t* __restrict__ Bt,
             const float* __restrict__ bias, bf16_t* __restrict__ Cb,
             int M, int N, int K) {
  __shared__ bf16_t Bs[64 * 64];         // 8 KB
  const int tid  = threadIdx.x;
  const int lane = tid & 63, w = tid >> 6;
  const int col = lane & 15, s16 = lane >> 4;
  const int nbn = N >> 6;
  const int cpx = gridDim.x >> 3;
  const int bid = (blockIdx.x & 7) * cpx + (blockIdx.x >> 3);
  const int bm = bid / nbn, bn = bid % nbn;
  const int wr = w >> 1, wc = w & 1;

  f32x4 acc[4][2];
#pragma unroll
  for (int i = 0; i < 4; ++i)
#pragma unroll
    for (int j = 0; j < 2; ++j) acc[i][j] = f32x4{0.f, 0.f, 0.f, 0.f};

  const long arow0 = (long)bm * 128;
  const long brow0 = (long)bn * 64;
  const bf16_t* aBase = A + (arow0 + wr * 64 + col) * (long)K;

  const int nt = K >> 6;
  for (int t = 0; t < nt; ++t) {
    const int k0 = t << 6;
    // A fragments direct from global (8 x bf16x8, contiguous per lane)
    bf16x8 af[2][4];
#pragma unroll
    for (int mi = 0; mi < 4; ++mi)
#pragma unroll
      for (int ks = 0; ks < 2; ++ks)
        af[ks][mi] = *(const bf16x8*)&aBase[(long)(mi * 16) * K + k0 +
                                            (ks * 4 + s16) * 8];
    // B tile -> LDS (2 DMA instrs), XOR-swizzled via pre-swizzled source
#pragma unroll
    for (int i = 0; i < 2; ++i) {
      const int c = i * 256 + tid;
      const int row = c >> 3, slot = c & 7;
      gload_lds16(Bt + (brow0 + row) * (long)K + k0 + ((slot ^ (row & 7)) << 3),
                  (char*)Bs + c * 16);
    }
    __syncthreads();        // drains vmcnt(0): B staged, A frags landed

    bf16x8 bfr[2][2];
#pragma unroll
    for (int ni = 0; ni < 2; ++ni) {
      const int row = wc * 32 + ni * 16 + col;
#pragma unroll
      for (int ks = 0; ks < 2; ++ks) {
        const int slot = ks * 4 + s16;
        bfr[ks][ni] = *(const bf16x8*)((char*)Bs + row * 128 +
                                       ((slot ^ (row & 7)) << 4));
      }
    }
#pragma unroll
    for (int ks = 0; ks < 2; ++ks)
#pragma unroll
      for (int mi = 0; mi < 4; ++mi)
#pragma unroll
        for (int ni = 0; ni < 2; ++ni)
          acc[mi][ni] = __builtin_amdgcn_mfma_f32_16x16x32_bf16(
              af[ks][mi], bfr[ks][ni], acc[mi][ni], 0, 0, 0);

    __syncthreads();        // all reads of Bs done before next overwrite
  }

  const int colb = bn * 64 + wc * 32 + col;
  const int rowb = bm * 128 + wr * 64 + (s16 << 2);
#pragma unroll
  for (int ni = 0; ni < 2; ++ni) {
    const int ccol = colb + ni * 16;
    const float bv = bias[ccol];
#pragma unroll
    for (int mi = 0; mi < 4; ++mi) {
      const int row = rowb + mi * 16;
#pragma unroll
      for (int r = 0; r < 4; ++r) {
        const float v = acc[mi][ni][r] + bv;
        const long idx = (long)(row + r) * N + ccol;
        if (EPI == 1) {
          Cb[idx] = (bf16_t)((float)Cb[idx] + v);    // bf16 residual RMW
        } else if (EPI == 2) {
          Cb[idx] = (bf16_t)v;
        } else {
          const float z = 0.7978845608028654f * (v + 0.044715f * v * v * v);
          Cb[idx] = (bf16_t)(v / (1.f + __expf(-2.f * z)));
        }
      }
    }
  }
}

// ---------------- big GEMM (qkv/fc): BM=256, BN=128, BK=64, 512 thr =
// 8 waves (4M x 2N, 64x64 out each), single-buffered 48 KB LDS (R13-proven,
// best-known). EPI: 2 bf16 store, 3 gelu->bf16.
template <int EPI>
__global__ __launch_bounds__(512, 4)
void gemm_bw(const bf16_t* __restrict__ A, const bf16_t* __restrict__ Bt,
             const float* __restrict__ bias, bf16_t* __restrict__ Cb,
             int M, int N, int K) {
  __shared__ bf16_t As[256 * 64];   // 32 KB
  __shared__ bf16_t Bs[128 * 64];   // 16 KB
  const int tid = threadIdx.x;
  const int lane = tid & 63, w = tid >> 6;
  const int col = lane & 15, s16 = lane >> 4;
  const int wm = w >> 1, wn = w & 1;        // 4M x 2N waves, 64x64 each
  const int nbn = N >> 7;
  const int cpx = gridDim.x >> 3;
  const int bid = (blockIdx.x & 7) * cpx + (blockIdx.x >> 3);
  const int bm = bid / nbn, bn = bid % nbn;
  const long arow0 = (long)bm * 256, brow0 = (long)bn * 128;

  f32x4 acc[4][4];
#pragma unroll
  for (int i = 0; i < 4; ++i)
#pragma unroll
    for (int j = 0; j < 4; ++j) acc[i][j] = f32x4{0.f, 0.f, 0.f, 0.f};

  const int nt = K >> 6;
  for (int t = 0; t < nt; ++t) {
    const int k0 = t << 6;
#pragma unroll
    for (int i = 0; i < 4; ++i) {           // A: 256 rows = 2048 slots
      const int c = i * 512 + tid;
      const int row = c >> 3, slot = c & 7;
      gload_lds16(A + (arow0 + row) * (long)K + k0 + ((slot ^ (row & 7)) << 3),
                  (char*)As + c * 16);
    }
#pragma unroll
    for (int i = 0; i < 2; ++i) {           // B: 128 rows = 1024 slots
      const int c = i * 512 + tid;
      const int row = c >> 3, slot = c & 7;
      gload_lds16(Bt + (brow0 + row) * (long)K + k0 + ((slot ^ (row & 7)) << 3),
                  (char*)Bs + c * 16);
    }
    __syncthreads();        // drains vmcnt(0): tile staged

    bf16x8 af[2][4], bfr[2][4];
#pragma unroll
    for (int mi = 0; mi < 4; ++mi) {
      const int row = wm * 64 + mi * 16 + col;
#pragma unroll
      for (int ks = 0; ks < 2; ++ks) {
        const int slot = ks * 4 + s16;
        af[ks][mi] = *(const bf16x8*)((char*)As + row * 128 +
                                      ((slot ^ (row & 7)) << 4));
      }
    }
#pragma unroll
    for (int ni = 0; ni < 4; ++ni) {
      const int row = wn * 64 + ni * 16 + col;
#pragma unroll
      for (int ks = 0; ks < 2; ++ks) {
        const int slot = ks * 4 + s16;
        bfr[ks][ni] = *(const bf16x8*)((char*)Bs + row * 128 +
                                       ((slot ^ (row & 7)) << 4));
      }
    }
#pragma unroll
    for (int ks = 0; ks < 2; ++ks)
#pragma unroll
      for (int mi = 0; mi < 4; ++mi)
#pragma unroll
        for (int ni = 0; ni < 4; ++ni)
          acc[mi][ni] = __builtin_amdgcn_mfma_f32_16x16x32_bf16(
              af[ks][mi], bfr[ks][ni], acc[mi][ni], 0, 0, 0);

    __syncthreads();
  }

  const int rowb = bm * 256 + wm * 64 + (s16 << 2);
  const int colb = bn * 128 + wn * 64 + col;
#pragma unroll
  for (int ni = 0; ni < 4; ++ni) {
    const int ccol = colb + ni * 16;
    const float bv = bias[ccol];
#pragma unroll
    for (int mi = 0; mi < 4; ++mi) {
      const int row = rowb + mi * 16;
#pragma unroll
      for (int r = 0; r < 4; ++r) {
        const float v = acc[mi][ni][r] + bv;
        if (EPI == 2) Cb[(long)(row + r) * N + ccol] = (bf16_t)v;
        else {
          const float z = 0.7978845608028654f * (v + 0.044715f * v * v * v);
          Cb[(long)(row + r) * N + ccol] = (bf16_t)(v / (1.f + __expf(-2.f * z)));
        }
      }
    }
  }
}

// ---------------- flash attention: paired q-tiles, double-buffered K/V,
// async-stage split (issue-early/write-late), one barrier per kt-iteration.
__global__ __launch_bounds__(256, 3)
void attn_kernel(const bf16_t* __restrict__ qkv, const float* __restrict__ mask,
                 bf16_t* __restrict__ out) {
  __shared__ bf16_t Kl[2][64 * 64];   // [key][dh], slot-swizzled
  __shared__ bf16_t Vt[2][64 * 64];   // [d][k],   slot-swizzled
  __shared__ bf16_t Pl[4][16 * 64];   // per-wave [q][key], slot-swizzled
  const int tid = threadIdx.x, lane = tid & 63, w = tid >> 6;
  const int col = lane & 15, s16 = lane >> 4, l7 = lane & 7;
  const int qp = blockIdx.x & 7;      // pair id: handles qt = qp and 15-qp
  const int bh = blockIdx.x >> 3;     // 0..95
  const int b = bh / 12, h = bh % 12;
  const int sw0 = (s16 ^ l7) << 4;
  const int sw1 = ((s16 + 4) ^ l7) << 4;
  char* const plw = (char*)&Pl[w][0];
  const long qkvb = (long)b * 1024 * 2304;

  auto stageK = [&](int buf, int k0) {
#pragma unroll
    for (int i = 0; i < 2; ++i) {
      const int c = i * 256 + tid;
      const int krow = c >> 3, slot = c & 7;
      gload_lds16(qkv + qkvb + (long)(k0 + krow) * 2304 + 768 + h * 64 +
                      ((slot ^ (krow & 7)) << 3),
                  (char*)&Kl[buf][0] + i * 4096 + w * 1024);
    }
  };
  auto loadV = [&](int k0, bf16x8& t0, bf16x8& t1) {
    const bf16_t* vbase = qkv + qkvb + 1536 + h * 64;
#pragma unroll
    for (int i = 0; i < 2; ++i) {
      const int c = i * 256 + tid;
      const int d = c & 63, koct = c >> 6;
      const bf16_t* vsrc = vbase + (long)(k0 + koct * 8) * 2304 + d;
      bf16x8 tv;
#pragma unroll
      for (int j = 0; j < 8; ++j) tv[j] = vsrc[(long)j * 2304];
      if (i == 0) t0 = tv; else t1 = tv;
    }
  };
  auto storeV = [&](int buf, const bf16x8& t0, const bf16x8& t1) {
#pragma unroll
    for (int i = 0; i < 2; ++i) {
      const int c = i * 256 + tid;
      const int d = c & 63, koct = c >> 6;
      *(bf16x8*)((char*)&Vt[buf][0] + d * 128 + ((koct ^ (d & 7)) << 4)) =
          (i == 0) ? t0 : t1;
    }
  };

#pragma unroll 1
  for (int pass = 0; pass < 2; ++pass) {
    const int qt = pass ? (15 - qp) : qp;
    const int qrow0 = qt * 64 + w * 16;
    const long rowQ = (long)(b * 1024 + qrow0 + col) * 2304 + h * 64;
    const bf16x8 aq0 = *(const bf16x8*)&qkv[rowQ + s16 * 8];
    const bf16x8 aq1 = *(const bf16x8*)&qkv[rowQ + 32 + s16 * 8];
    const int qb = qrow0 + s16 * 4;
    const float* mrow = mask + ((long)b * 1024 + qb) * 1024;

    auto loadM = [&](int k0, float (&m)[4][4]) {
#pragma unroll
      for (int g = 0; g < 4; ++g)
#pragma unroll
        for (int r = 0; r < 4; ++r)
          m[g][r] = mrow[(long)r * 1024 + k0 + g * 16 + col];
    };

    float m_run[4], l_run[4];
    f32x4 o_acc[4];
#pragma unroll
    for (int r = 0; r < 4; ++r) { m_run[r] = -INFINITY; l_run[r] = 0.f; }
#pragma unroll
    for (int go = 0; go < 4; ++go) o_acc[go] = f32x4{0.f, 0.f, 0.f, 0.f};

    bf16x8 tv0, tv1;
    stageK(0, 0);
    loadV(0, tv0, tv1);
    storeV(0, tv0, tv1);
    float msk[4][4];
    loadM(0, msk);
    __syncthreads();

#pragma unroll 1
    for (int kt = 0; kt <= qt; ++kt) {
      const int cur = kt & 1;
      const bool more = kt < qt;
      const int k0 = kt * 64;
      float mnx[4][4];
      if (more) {
        stageK(cur ^ 1, k0 + 64);
        loadV(k0 + 64, tv0, tv1);
        loadM(k0 + 64, mnx);
      }

      f32x4 sf[4];
      __builtin_amdgcn_s_setprio(1);
#pragma unroll
      for (int g = 0; g < 4; ++g) {
        const int rbyte = (g * 16 + col) * 128;
        bf16x8 bk0 = *(const bf16x8*)((char*)&Kl[cur][0] + rbyte + sw0);
        bf16x8 bk1 = *(const bf16x8*)((char*)&Kl[cur][0] + rbyte + sw1);
        f32x4 z = f32x4{0.f, 0.f, 0.f, 0.f};
        z = __builtin_amdgcn_mfma_f32_16x16x32_bf16(aq0, bk0, z, 0, 0, 0);
        z = __builtin_amdgcn_mfma_f32_16x16x32_bf16(aq1, bk1, z, 0, 0, 0);
        sf[g] = z;
      }
      __builtin_amdgcn_s_setprio(0);

      const bool diag = (kt == qt);
      float sv[4][4];
#pragma unroll
      for (int g = 0; g < 4; ++g)
#pragma unroll
        for (int r = 0; r < 4; ++r) {
          float s = sf[g][r] * 0.125f + msk[g][r];
          if (diag && (k0 + g * 16 + col) > (qb + r)) s = -INFINITY;
          sv[g][r] = s;
        }
#pragma unroll
      for (int r = 0; r < 4; ++r) {
        float mx = fmaxf(fmaxf(sv[0][r], sv[1][r]), fmaxf(sv[2][r], sv[3][r]));
#pragma unroll
        for (int o = 8; o; o >>= 1) mx = fmaxf(mx, __shfl_xor(mx, o));
        const float m_new = fmaxf(m_run[r], mx);
        const float f = __expf(m_run[r] - m_new);
        m_run[r] = m_new;
        float sum = 0.f;
#pragma unroll
        for (int g = 0; g < 4; ++g) {
          const float p = __expf(sv[g][r] - m_new);
          sv[g][r] = p;
          sum += p;
        }
#pragma unroll
        for (int o = 8; o; o >>= 1) sum += __shfl_xor(sum, o);
        l_run[r] = l_run[r] * f + sum;
#pragma unroll
        for (int go = 0; go < 4; ++go) o_acc[go][r] *= f;
      }

#pragma unroll
      for (int g = 0; g < 4; ++g) {
        const int ks = 2 * g + (col >> 3);
#pragma unroll
        for (int r = 0; r < 4; ++r) {
          const int qr = s16 * 4 + r;
          *(bf16_t*)(plw + qr * 128 + ((ks ^ (qr & 7)) << 4) + l7 * 2) = (bf16_t)sv[g][r];
        }
      }
      const bf16x8 pa0 = *(const bf16x8*)(plw + col * 128 + sw0);
      const bf16x8 pa1 = *(const bf16x8*)(plw + col * 128 + sw1);
      __builtin_amdgcn_s_setprio(1);
#pragma unroll
      for (int go = 0; go < 4; ++go) {
        const int dbyte = (go * 16 + col) * 128;
        bf16x8 bv0 = *(const bf16x8*)((char*)&Vt[cur][0] + dbyte + sw0);
        bf16x8 bv1 = *(const bf16x8*)((char*)&Vt[cur][0] + dbyte + sw1);
        o_acc[go] = __builtin_amdgcn_mfma_f32_16x16x32_bf16(pa0, bv0, o_acc[go], 0, 0, 0);
        o_acc[go] = __builtin_amdgcn_mfma_f32_16x16x32_bf16(pa1, bv1, o_acc[go], 0, 0, 0);
      }
      __builtin_amdgcn_s_setprio(0);

      if (more) {
        storeV(cur ^ 1, tv0, tv1);
#pragma unroll
        for (int g = 0; g < 4; ++g)
#pragma unroll
          for (int r = 0; r < 4; ++r) msk[g][r] = mnx[g][r];
      }
      __syncthreads();
    }

    float inv[4];
#pragma unroll
    for (int r = 0; r < 4; ++r) inv[r] = 1.f / l_run[r];
#pragma unroll
    for (int go = 0; go < 4; ++go)
#pragma unroll
      for (int r = 0; r < 4; ++r)
        out[(long)(b * 1024 + qb + r) * 768 + h * 64 + go * 16 + col] =
            (bf16_t)(o_acc[go][r] * inv[r]);
  }
}

// ---------------- host
extern "C" void kernel_launch(void* const* d_in, const int* in_sizes, int n_in,
                              void* d_out, int out_size, void* d_ws, size_t ws_size,
                              hipStream_t stream) {
  const int*   x_ids = (const int*)d_in[0];
  const float* mask  = (const float*)d_in[1];
  const float* wte   = (const float*)d_in[2];
  const float* wpe   = (const float*)d_in[3];
  const float* ln1_g = (const float*)d_in[4];
  const float* ln1_b = (const float*)d_in[5];
  const float* qkv_w = (const float*)d_in[6];
  const float* qkv_b = (const float*)d_in[7];
  const float* ao_w  = (const float*)d_in[8];
  const float* ao_b  = (const float*)d_in[9];
  const float* ln2_g = (const float*)d_in[10];
  const float* ln2_b = (const float*)d_in[11];
  const float* fc_w  = (const float*)d_in[12];
  const float* fc_b  = (const float*)d_in[13];
  const float* op_w  = (const float*)d_in[14];
  const float* op_b  = (const float*)d_in[15];
  const float* lnf_g = (const float*)d_in[16];
  const float* lnf_b = (const float*)d_in[17];

  char* ws = (char*)d_ws;
  size_t off = 0;
  auto alloc = [&](size_t bytes) {
    char* p = ws + off;
    off += (bytes + 255) & ~(size_t)255;
    return p;
  };
  bf16_t* wqT = (bf16_t*)alloc(6ull * 2304 * 768 * 2);
  bf16_t* waT = (bf16_t*)alloc(6ull * 768 * 768 * 2);
  bf16_t* wfT = (bf16_t*)alloc(6ull * 3072 * 768 * 2);
  bf16_t* woT = (bf16_t*)alloc(6ull * 768 * 3072 * 2);
  bf16_t* h   = (bf16_t*)alloc(8192ull * 768 * 2);     // residual stream, bf16
  bf16_t* xb  = (bf16_t*)alloc(8192ull * 768 * 2);
  bf16_t* qkv = (bf16_t*)alloc(8192ull * 2304 * 2);
  bf16_t* abf = (bf16_t*)alloc(8192ull * 768 * 2);
  bf16_t* fb  = (bf16_t*)alloc(8192ull * 3072 * 2);
  if (off > ws_size) return;

  // batched transposes: one launch per weight class (z = layer)
  transpose_cast<<<dim3(768 / 32, 2304 / 32, 6), 256, 0, stream>>>(qkv_w, wqT, 768, 2304);
  transpose_cast<<<dim3(768 / 32, 768 / 32, 6), 256, 0, stream>>>(ao_w, waT, 768, 768);
  transpose_cast<<<dim3(768 / 32, 3072 / 32, 6), 256, 0, stream>>>(fc_w, wfT, 768, 3072);
  transpose_cast<<<dim3(3072 / 32, 768 / 32, 6), 256, 0, stream>>>(op_w, woT, 3072, 768);

  embed_kernel<<<3072, 256, 0, stream>>>(x_ids, wte, wpe, h);

  for (int l = 0; l < 6; ++l) {
    ln_kernel<true><<<2048, 256, 0, stream>>>(h, ln1_g + l * 768, ln1_b + l * 768, xb, nullptr);
    // qkv: 8192x2304 K=768 -> 256x128 tile, grid 32*18 = 576
    gemm_bw<2><<<576, 512, 0, stream>>>(xb, wqT + (long)l * 2304 * 768,
                                        qkv_b + l * 2304, qkv, 8192, 2304, 768);
    attn_kernel<<<768, 256, 0, stream>>>(qkv, mask, abf);
    // ao: 8192x768 K=768 -> BN=64 grid 768, bf16 residual RMW (A direct)
    gemm_bt<1><<<768, 256, 0, stream>>>(abf, waT + (long)l * 768 * 768,
                                        ao_b + l * 768, h, 8192, 768, 768);
    ln_kernel<true><<<2048, 256, 0, stream>>>(h, ln2_g + l * 768, ln2_b + l * 768, xb, nullptr);
    // fc: 8192x3072 K=768 -> 256x128 tile, grid 32*24 = 768 (exactly 3/CU)
    gemm_bw<3><<<768, 512, 0, stream>>>(xb, wfT + (long)l * 3072 * 768,
                                        fc_b + l * 3072, fb, 8192, 3072, 768);
    // op: 8192x768 K=3072 -> BN=64 grid 768, bf16 residual RMW (A direct)
    gemm_bt<1><<<768, 256, 0, stream>>>(fb, woT + (long)l * 768 * 3072,
                                        op_b + l * 768, h, 8192, 768, 3072);
  }

  ln_kernel<false><<<2048, 256, 0, stream>>>(h, lnf_g, lnf_b, nullptr, (float*)d_out);
}

// Round 16
// 1599.460 us; speedup vs baseline: 1.4448x; 1.4448x over previous
//
#include <hip/hip_runtime.h>
#include <hip/hip_bf16.h>

typedef __bf16 bf16_t;
typedef __bf16 bf16x8 __attribute__((ext_vector_type(8)));
typedef __bf16 bf16x4 __attribute__((ext_vector_type(4)));
typedef float  f32x4  __attribute__((ext_vector_type(4)));

#define DEV __device__ __forceinline__

DEV void gload_lds16(const void* g, void* l) {
  __builtin_amdgcn_global_load_lds(
      (__attribute__((address_space(1))) void*)(void*)g,
      (__attribute__((address_space(3))) void*)l, 16, 0, 0);
}

// ---------------- weight transpose+cast (batched over layers via z):
// in fp32 [L][K][N] -> out bf16 [L][N][K]. float4 reads, bf16x4 writes.
__global__ __launch_bounds__(256)
void transpose_cast(const float* __restrict__ in, bf16_t* __restrict__ out,
                    int K, int N) {
  __shared__ float tile[32][33];
  const long z = blockIdx.z;
  const float* inz = in + z * (long)K * N;
  bf16_t* outz = out + z * (long)N * K;
  const int k0 = blockIdx.x * 32;
  const int n0 = blockIdx.y * 32;
  const int tx = threadIdx.x & 7;        // n-chunk (x4)
  const int ty = threadIdx.x >> 3;       // 0..31
  const f32x4 ld = *(const f32x4*)&inz[(long)(k0 + ty) * N + n0 + tx * 4];
#pragma unroll
  for (int j = 0; j < 4; ++j) tile[ty][tx * 4 + j] = ld[j];
  __syncthreads();
  bf16x4 st;
#pragma unroll
  for (int j = 0; j < 4; ++j) st[j] = (bf16_t)tile[tx * 4 + j][ty];
  *(bf16x4*)&outz[(long)(n0 + ty) * K + k0 + tx * 4] = st;
}

// ---------------- embedding: h = wte[ids] + wpe[s]  (bf16 out, 8/thread)
__global__ __launch_bounds__(256)
void embed_kernel(const int* __restrict__ ids, const float* __restrict__ wte,
                  const float* __restrict__ wpe, bf16_t* __restrict__ h) {
  const int t = blockIdx.x * 256 + threadIdx.x;     // < 8192*96
  const int row = t / 96;
  const int c8  = (t % 96) * 8;
  const int s   = row & 1023;
  const float* wr = wte + (long)ids[row] * 768 + c8;
  const float* pr = wpe + (long)s * 768 + c8;
  bf16x8 o;
#pragma unroll
  for (int j = 0; j < 8; ++j) o[j] = (bf16_t)(wr[j] + pr[j]);
  *(bf16x8*)&h[(long)row * 768 + c8] = o;
}

// ---------------- layernorm: wave per row, 4 rows/block, vector loads,
// wave-only shfl reduction. x bf16; out bf16 (ob) or f32 (of).
template <bool BF16OUT>
__global__ __launch_bounds__(256)
void ln_kernel(const bf16_t* __restrict__ x, const float* __restrict__ g,
               const float* __restrict__ b, bf16_t* __restrict__ ob,
               float* __restrict__ of) {
  const int lane = threadIdx.x & 63;
  const long row = blockIdx.x * 4 + (threadIdx.x >> 6);
  const bf16_t* xr = x + row * 768;
  const bf16x8 v8 = *(const bf16x8*)&xr[lane * 8];          // cols [0,512)
  const bf16x4 v4 = *(const bf16x4*)&xr[512 + lane * 4];    // cols [512,768)
  float vv[12];
#pragma unroll
  for (int j = 0; j < 8; ++j) vv[j] = (float)v8[j];
#pragma unroll
  for (int j = 0; j < 4; ++j) vv[8 + j] = (float)v4[j];
  float s = 0.f, sq = 0.f;
#pragma unroll
  for (int j = 0; j < 12; ++j) { s += vv[j]; sq += vv[j] * vv[j]; }
#pragma unroll
  for (int o = 32; o; o >>= 1) { s += __shfl_xor(s, o); sq += __shfl_xor(sq, o); }
  const float mean = s * (1.f / 768.f);
  const float rs = rsqrtf(sq * (1.f / 768.f) - mean * mean + 1e-5f);
  if (BF16OUT) {
    bf16x8 o8; bf16x4 o4;
#pragma unroll
    for (int j = 0; j < 8; ++j) {
      const int col = lane * 8 + j;
      o8[j] = (bf16_t)((vv[j] - mean) * rs * g[col] + b[col]);
    }
#pragma unroll
    for (int j = 0; j < 4; ++j) {
      const int col = 512 + lane * 4 + j;
      o4[j] = (bf16_t)((vv[8 + j] - mean) * rs * g[col] + b[col]);
    }
    *(bf16x8*)&ob[row * 768 + lane * 8] = o8;
    *(bf16x4*)&ob[row * 768 + 512 + lane * 4] = o4;
  } else {
#pragma unroll
    for (int j = 0; j < 8; ++j) {
      const int col = lane * 8 + j;
      of[row * 768 + col] = (vv[j] - mean) * rs * g[col] + b[col];
    }
#pragma unroll
    for (int j = 0; j < 4; ++j) {
      const int col = 512 + lane * 4 + j;
      of[row * 768 + col] = (vv[8 + j] - mean) * rs * g[col] + b[col];
    }
  }
}

// ---------------- narrow GEMM (ao/op): BM=128, BN=64, BK=64, 256 thr,
// single-buffered 24 KB LDS (4 blocks/CU), A+B both LDS-staged (R13-proven;
// R15 showed A-direct is catastrophic: uncoalesced 16B frag loads).
// EPI: 1 = bf16 residual RMW, 2 = bf16 store, 3 = gelu->bf16.
template <int EPI, int BN>
__global__ __launch_bounds__(256, 4)
void gemm_bt(const bf16_t* __restrict__ A, const bf16_t* __restrict__ Bt,
             const float* __restrict__ bias, bf16_t* __restrict__ Cb,
             int M, int N, int K) {
  constexpr int NI = BN / 32;            // n-fragments per wave
  __shared__ bf16_t As[128 * 64];
  __shared__ bf16_t Bs[BN * 64];
  const int tid  = threadIdx.x;
  const int lane = tid & 63, w = tid >> 6;
  const int col = lane & 15, s16 = lane >> 4;
  const int nbn = N / BN;
  const int cpx = gridDim.x >> 3;
  const int bid = (blockIdx.x & 7) * cpx + (blockIdx.x >> 3);
  const int bm = bid / nbn, bn = bid % nbn;
  const int wr = w >> 1, wc = w & 1;

  f32x4 acc[4][NI];
#pragma unroll
  for (int i = 0; i < 4; ++i)
#pragma unroll
    for (int j = 0; j < NI; ++j) acc[i][j] = f32x4{0.f, 0.f, 0.f, 0.f};

  const long arow0 = (long)bm * 128;
  const long brow0 = (long)bn * BN;

  const int nt = K >> 6;
  for (int t = 0; t < nt; ++t) {
    const int k0 = t << 6;
#pragma unroll
    for (int i = 0; i < 4; ++i) {
      const int c = i * 256 + tid;
      const int row = c >> 3, slot = c & 7;
      gload_lds16(A + (arow0 + row) * (long)K + k0 + ((slot ^ (row & 7)) << 3),
                  (char*)As + c * 16);
    }
#pragma unroll
    for (int i = 0; i < BN / 32; ++i) {
      const int c = i * 256 + tid;
      const int row = c >> 3, slot = c & 7;
      gload_lds16(Bt + (brow0 + row) * (long)K + k0 + ((slot ^ (row & 7)) << 3),
                  (char*)Bs + c * 16);
    }
    __syncthreads();        // drains vmcnt(0): tile staged

    bf16x8 af[2][4], bfr[2][NI];
#pragma unroll
    for (int mi = 0; mi < 4; ++mi) {
      const int row = wr * 64 + mi * 16 + col;
#pragma unroll
      for (int ks = 0; ks < 2; ++ks) {
        const int slot = ks * 4 + s16;
        af[ks][mi] = *(const bf16x8*)((char*)As + row * 128 +
                                      ((slot ^ (row & 7)) << 4));
      }
    }
#pragma unroll
    for (int ni = 0; ni < NI; ++ni) {
      const int row = wc * (BN / 2) + ni * 16 + col;
#pragma unroll
      for (int ks = 0; ks < 2; ++ks) {
        const int slot = ks * 4 + s16;
        bfr[ks][ni] = *(const bf16x8*)((char*)Bs + row * 128 +
                                       ((slot ^ (row & 7)) << 4));
      }
    }
#pragma unroll
    for (int ks = 0; ks < 2; ++ks)
#pragma unroll
      for (int mi = 0; mi < 4; ++mi)
#pragma unroll
        for (int ni = 0; ni < NI; ++ni)
          acc[mi][ni] = __builtin_amdgcn_mfma_f32_16x16x32_bf16(
              af[ks][mi], bfr[ks][ni], acc[mi][ni], 0, 0, 0);

    __syncthreads();        // all reads done before next stage overwrites
  }

  const int colb = bn * BN + wc * (BN / 2) + col;
  const int rowb = bm * 128 + wr * 64 + (s16 << 2);
#pragma unroll
  for (int ni = 0; ni < NI; ++ni) {
    const int ccol = colb + ni * 16;
    const float bv = bias[ccol];
#pragma unroll
    for (int mi = 0; mi < 4; ++mi) {
      const int row = rowb + mi * 16;
#pragma unroll
      for (int r = 0; r < 4; ++r) {
        const float v = acc[mi][ni][r] + bv;
        const long idx = (long)(row + r) * N + ccol;
        if (EPI == 1) {
          Cb[idx] = (bf16_t)((float)Cb[idx] + v);    // bf16 residual RMW
        } else if (EPI == 2) {
          Cb[idx] = (bf16_t)v;
        } else {
          const float z = 0.7978845608028654f * (v + 0.044715f * v * v * v);
          Cb[idx] = (bf16_t)(v / (1.f + __expf(-2.f * z)));
        }
      }
    }
  }
}

// ---------------- big GEMM (qkv/fc): BM=256, BN=128, BK=64, 512 thr =
// 8 waves (4M x 2N, 64x64 out each), single-buffered 48 KB LDS (R13-proven).
// EPI: 2 bf16 store, 3 gelu->bf16.
template <int EPI>
__global__ __launch_bounds__(512, 4)
void gemm_bw(const bf16_t* __restrict__ A, const bf16_t* __restrict__ Bt,
             const float* __restrict__ bias, bf16_t* __restrict__ Cb,
             int M, int N, int K) {
  __shared__ bf16_t As[256 * 64];   // 32 KB
  __shared__ bf16_t Bs[128 * 64];   // 16 KB
  const int tid = threadIdx.x;
  const int lane = tid & 63, w = tid >> 6;
  const int col = lane & 15, s16 = lane >> 4;
  const int wm = w >> 1, wn = w & 1;        // 4M x 2N waves, 64x64 each
  const int nbn = N >> 7;
  const int cpx = gridDim.x >> 3;
  const int bid = (blockIdx.x & 7) * cpx + (blockIdx.x >> 3);
  const int bm = bid / nbn, bn = bid % nbn;
  const long arow0 = (long)bm * 256, brow0 = (long)bn * 128;

  f32x4 acc[4][4];
#pragma unroll
  for (int i = 0; i < 4; ++i)
#pragma unroll
    for (int j = 0; j < 4; ++j) acc[i][j] = f32x4{0.f, 0.f, 0.f, 0.f};

  const int nt = K >> 6;
  for (int t = 0; t < nt; ++t) {
    const int k0 = t << 6;
#pragma unroll
    for (int i = 0; i < 4; ++i) {           // A: 256 rows = 2048 slots
      const int c = i * 512 + tid;
      const int row = c >> 3, slot = c & 7;
      gload_lds16(A + (arow0 + row) * (long)K + k0 + ((slot ^ (row & 7)) << 3),
                  (char*)As + c * 16);
    }
#pragma unroll
    for (int i = 0; i < 2; ++i) {           // B: 128 rows = 1024 slots
      const int c = i * 512 + tid;
      const int row = c >> 3, slot = c & 7;
      gload_lds16(Bt + (brow0 + row) * (long)K + k0 + ((slot ^ (row & 7)) << 3),
                  (char*)Bs + c * 16);
    }
    __syncthreads();        // drains vmcnt(0): tile staged

    bf16x8 af[2][4], bfr[2][4];
#pragma unroll
    for (int mi = 0; mi < 4; ++mi) {
      const int row = wm * 64 + mi * 16 + col;
#pragma unroll
      for (int ks = 0; ks < 2; ++ks) {
        const int slot = ks * 4 + s16;
        af[ks][mi] = *(const bf16x8*)((char*)As + row * 128 +
                                      ((slot ^ (row & 7)) << 4));
      }
    }
#pragma unroll
    for (int ni = 0; ni < 4; ++ni) {
      const int row = wn * 64 + ni * 16 + col;
#pragma unroll
      for (int ks = 0; ks < 2; ++ks) {
        const int slot = ks * 4 + s16;
        bfr[ks][ni] = *(const bf16x8*)((char*)Bs + row * 128 +
                                       ((slot ^ (row & 7)) << 4));
      }
    }
#pragma unroll
    for (int ks = 0; ks < 2; ++ks)
#pragma unroll
      for (int mi = 0; mi < 4; ++mi)
#pragma unroll
        for (int ni = 0; ni < 4; ++ni)
          acc[mi][ni] = __builtin_amdgcn_mfma_f32_16x16x32_bf16(
              af[ks][mi], bfr[ks][ni], acc[mi][ni], 0, 0, 0);

    __syncthreads();
  }

  const int rowb = bm * 256 + wm * 64 + (s16 << 2);
  const int colb = bn * 128 + wn * 64 + col;
#pragma unroll
  for (int ni = 0; ni < 4; ++ni) {
    const int ccol = colb + ni * 16;
    const float bv = bias[ccol];
#pragma unroll
    for (int mi = 0; mi < 4; ++mi) {
      const int row = rowb + mi * 16;
#pragma unroll
      for (int r = 0; r < 4; ++r) {
        const float v = acc[mi][ni][r] + bv;
        if (EPI == 2) Cb[(long)(row + r) * N + ccol] = (bf16_t)v;
        else {
          const float z = 0.7978845608028654f * (v + 0.044715f * v * v * v);
          Cb[(long)(row + r) * N + ccol] = (bf16_t)(v / (1.f + __expf(-2.f * z)));
        }
      }
    }
  }
}

// ---------------- flash attention: paired q-tiles, double-buffered K/V,
// async-stage split (issue-early/write-late), one barrier per kt-iteration.
__global__ __launch_bounds__(256, 3)
void attn_kernel(const bf16_t* __restrict__ qkv, const float* __restrict__ mask,
                 bf16_t* __restrict__ out) {
  __shared__ bf16_t Kl[2][64 * 64];   // [key][dh], slot-swizzled
  __shared__ bf16_t Vt[2][64 * 64];   // [d][k],   slot-swizzled
  __shared__ bf16_t Pl[4][16 * 64];   // per-wave [q][key], slot-swizzled
  const int tid = threadIdx.x, lane = tid & 63, w = tid >> 6;
  const int col = lane & 15, s16 = lane >> 4, l7 = lane & 7;
  const int qp = blockIdx.x & 7;      // pair id: handles qt = qp and 15-qp
  const int bh = blockIdx.x >> 3;     // 0..95
  const int b = bh / 12, h = bh % 12;
  const int sw0 = (s16 ^ l7) << 4;
  const int sw1 = ((s16 + 4) ^ l7) << 4;
  char* const plw = (char*)&Pl[w][0];
  const long qkvb = (long)b * 1024 * 2304;

  auto stageK = [&](int buf, int k0) {
#pragma unroll
    for (int i = 0; i < 2; ++i) {
      const int c = i * 256 + tid;
      const int krow = c >> 3, slot = c & 7;
      gload_lds16(qkv + qkvb + (long)(k0 + krow) * 2304 + 768 + h * 64 +
                      ((slot ^ (krow & 7)) << 3),
                  (char*)&Kl[buf][0] + i * 4096 + w * 1024);
    }
  };
  auto loadV = [&](int k0, bf16x8& t0, bf16x8& t1) {
    const bf16_t* vbase = qkv + qkvb + 1536 + h * 64;
#pragma unroll
    for (int i = 0; i < 2; ++i) {
      const int c = i * 256 + tid;
      const int d = c & 63, koct = c >> 6;
      const bf16_t* vsrc = vbase + (long)(k0 + koct * 8) * 2304 + d;
      bf16x8 tv;
#pragma unroll
      for (int j = 0; j < 8; ++j) tv[j] = vsrc[(long)j * 2304];
      if (i == 0) t0 = tv; else t1 = tv;
    }
  };
  auto storeV = [&](int buf, const bf16x8& t0, const bf16x8& t1) {
#pragma unroll
    for (int i = 0; i < 2; ++i) {
      const int c = i * 256 + tid;
      const int d = c & 63, koct = c >> 6;
      *(bf16x8*)((char*)&Vt[buf][0] + d * 128 + ((koct ^ (d & 7)) << 4)) =
          (i == 0) ? t0 : t1;
    }
  };

#pragma unroll 1
  for (int pass = 0; pass < 2; ++pass) {
    const int qt = pass ? (15 - qp) : qp;
    const int qrow0 = qt * 64 + w * 16;
    const long rowQ = (long)(b * 1024 + qrow0 + col) * 2304 + h * 64;
    const bf16x8 aq0 = *(const bf16x8*)&qkv[rowQ + s16 * 8];
    const bf16x8 aq1 = *(const bf16x8*)&qkv[rowQ + 32 + s16 * 8];
    const int qb = qrow0 + s16 * 4;
    const float* mrow = mask + ((long)b * 1024 + qb) * 1024;

    auto loadM = [&](int k0, float (&m)[4][4]) {
#pragma unroll
      for (int g = 0; g < 4; ++g)
#pragma unroll
        for (int r = 0; r < 4; ++r)
          m[g][r] = mrow[(long)r * 1024 + k0 + g * 16 + col];
    };

    float m_run[4], l_run[4];
    f32x4 o_acc[4];
#pragma unroll
    for (int r = 0; r < 4; ++r) { m_run[r] = -INFINITY; l_run[r] = 0.f; }
#pragma unroll
    for (int go = 0; go < 4; ++go) o_acc[go] = f32x4{0.f, 0.f, 0.f, 0.f};

    bf16x8 tv0, tv1;
    stageK(0, 0);
    loadV(0, tv0, tv1);
    storeV(0, tv0, tv1);
    float msk[4][4];
    loadM(0, msk);
    __syncthreads();

#pragma unroll 1
    for (int kt = 0; kt <= qt; ++kt) {
      const int cur = kt & 1;
      const bool more = kt < qt;
      const int k0 = kt * 64;
      float mnx[4][4];
      if (more) {
        stageK(cur ^ 1, k0 + 64);
        loadV(k0 + 64, tv0, tv1);
        loadM(k0 + 64, mnx);
      }

      f32x4 sf[4];
      __builtin_amdgcn_s_setprio(1);
#pragma unroll
      for (int g = 0; g < 4; ++g) {
        const int rbyte = (g * 16 + col) * 128;
        bf16x8 bk0 = *(const bf16x8*)((char*)&Kl[cur][0] + rbyte + sw0);
        bf16x8 bk1 = *(const bf16x8*)((char*)&Kl[cur][0] + rbyte + sw1);
        f32x4 z = f32x4{0.f, 0.f, 0.f, 0.f};
        z = __builtin_amdgcn_mfma_f32_16x16x32_bf16(aq0, bk0, z, 0, 0, 0);
        z = __builtin_amdgcn_mfma_f32_16x16x32_bf16(aq1, bk1, z, 0, 0, 0);
        sf[g] = z;
      }
      __builtin_amdgcn_s_setprio(0);

      const bool diag = (kt == qt);
      float sv[4][4];
#pragma unroll
      for (int g = 0; g < 4; ++g)
#pragma unroll
        for (int r = 0; r < 4; ++r) {
          float s = sf[g][r] * 0.125f + msk[g][r];
          if (diag && (k0 + g * 16 + col) > (qb + r)) s = -INFINITY;
          sv[g][r] = s;
        }
#pragma unroll
      for (int r = 0; r < 4; ++r) {
        float mx = fmaxf(fmaxf(sv[0][r], sv[1][r]), fmaxf(sv[2][r], sv[3][r]));
#pragma unroll
        for (int o = 8; o; o >>= 1) mx = fmaxf(mx, __shfl_xor(mx, o));
        const float m_new = fmaxf(m_run[r], mx);
        const float f = __expf(m_run[r] - m_new);
        m_run[r] = m_new;
        float sum = 0.f;
#pragma unroll
        for (int g = 0; g < 4; ++g) {
          const float p = __expf(sv[g][r] - m_new);
          sv[g][r] = p;
          sum += p;
        }
#pragma unroll
        for (int o = 8; o; o >>= 1) sum += __shfl_xor(sum, o);
        l_run[r] = l_run[r] * f + sum;
#pragma unroll
        for (int go = 0; go < 4; ++go) o_acc[go][r] *= f;
      }

#pragma unroll
      for (int g = 0; g < 4; ++g) {
        const int ks = 2 * g + (col >> 3);
#pragma unroll
        for (int r = 0; r < 4; ++r) {
          const int qr = s16 * 4 + r;
          *(bf16_t*)(plw + qr * 128 + ((ks ^ (qr & 7)) << 4) + l7 * 2) = (bf16_t)sv[g][r];
        }
      }
      const bf16x8 pa0 = *(const bf16x8*)(plw + col * 128 + sw0);
      const bf16x8 pa1 = *(const bf16x8*)(plw + col * 128 + sw1);
      __builtin_amdgcn_s_setprio(1);
#pragma unroll
      for (int go = 0; go < 4; ++go) {
        const int dbyte = (go * 16 + col) * 128;
        bf16x8 bv0 = *(const bf16x8*)((char*)&Vt[cur][0] + dbyte + sw0);
        bf16x8 bv1 = *(const bf16x8*)((char*)&Vt[cur][0] + dbyte + sw1);
        o_acc[go] = __builtin_amdgcn_mfma_f32_16x16x32_bf16(pa0, bv0, o_acc[go], 0, 0, 0);
        o_acc[go] = __builtin_amdgcn_mfma_f32_16x16x32_bf16(pa1, bv1, o_acc[go], 0, 0, 0);
      }
      __builtin_amdgcn_s_setprio(0);

      if (more) {
        storeV(cur ^ 1, tv0, tv1);
#pragma unroll
        for (int g = 0; g < 4; ++g)
#pragma unroll
          for (int r = 0; r < 4; ++r) msk[g][r] = mnx[g][r];
      }
      __syncthreads();
    }

    float inv[4];
#pragma unroll
    for (int r = 0; r < 4; ++r) inv[r] = 1.f / l_run[r];
#pragma unroll
    for (int go = 0; go < 4; ++go)
#pragma unroll
      for (int r = 0; r < 4; ++r)
        out[(long)(b * 1024 + qb + r) * 768 + h * 64 + go * 16 + col] =
            (bf16_t)(o_acc[go][r] * inv[r]);
  }
}

// ---------------- host
extern "C" void kernel_launch(void* const* d_in, const int* in_sizes, int n_in,
                              void* d_out, int out_size, void* d_ws, size_t ws_size,
                              hipStream_t stream) {
  const int*   x_ids = (const int*)d_in[0];
  const float* mask  = (const float*)d_in[1];
  const float* wte   = (const float*)d_in[2];
  const float* wpe   = (const float*)d_in[3];
  const float* ln1_g = (const float*)d_in[4];
  const float* ln1_b = (const float*)d_in[5];
  const float* qkv_w = (const float*)d_in[6];
  const float* qkv_b = (const float*)d_in[7];
  const float* ao_w  = (const float*)d_in[8];
  const float* ao_b  = (const float*)d_in[9];
  const float* ln2_g = (const float*)d_in[10];
  const float* ln2_b = (const float*)d_in[11];
  const float* fc_w  = (const float*)d_in[12];
  const float* fc_b  = (const float*)d_in[13];
  const float* op_w  = (const float*)d_in[14];
  const float* op_b  = (const float*)d_in[15];
  const float* lnf_g = (const float*)d_in[16];
  const float* lnf_b = (const float*)d_in[17];

  char* ws = (char*)d_ws;
  size_t off = 0;
  auto alloc = [&](size_t bytes) {
    char* p = ws + off;
    off += (bytes + 255) & ~(size_t)255;
    return p;
  };
  bf16_t* wqT = (bf16_t*)alloc(6ull * 2304 * 768 * 2);
  bf16_t* waT = (bf16_t*)alloc(6ull * 768 * 768 * 2);
  bf16_t* wfT = (bf16_t*)alloc(6ull * 3072 * 768 * 2);
  bf16_t* woT = (bf16_t*)alloc(6ull * 768 * 3072 * 2);
  bf16_t* h   = (bf16_t*)alloc(8192ull * 768 * 2);     // residual stream, bf16
  bf16_t* xb  = (bf16_t*)alloc(8192ull * 768 * 2);
  bf16_t* qkv = (bf16_t*)alloc(8192ull * 2304 * 2);
  bf16_t* abf = (bf16_t*)alloc(8192ull * 768 * 2);
  bf16_t* fb  = (bf16_t*)alloc(8192ull * 3072 * 2);
  if (off > ws_size) return;

  // batched transposes: one launch per weight class (z = layer)
  transpose_cast<<<dim3(768 / 32, 2304 / 32, 6), 256, 0, stream>>>(qkv_w, wqT, 768, 2304);
  transpose_cast<<<dim3(768 / 32, 768 / 32, 6), 256, 0, stream>>>(ao_w, waT, 768, 768);
  transpose_cast<<<dim3(768 / 32, 3072 / 32, 6), 256, 0, stream>>>(fc_w, wfT, 768, 3072);
  transpose_cast<<<dim3(3072 / 32, 768 / 32, 6), 256, 0, stream>>>(op_w, woT, 3072, 768);

  embed_kernel<<<3072, 256, 0, stream>>>(x_ids, wte, wpe, h);

  for (int l = 0; l < 6; ++l) {
    ln_kernel<true><<<2048, 256, 0, stream>>>(h, ln1_g + l * 768, ln1_b + l * 768, xb, nullptr);
    // qkv: 8192x2304 K=768 -> 256x128 tile, grid 32*18 = 576
    gemm_bw<2><<<576, 512, 0, stream>>>(xb, wqT + (long)l * 2304 * 768,
                                        qkv_b + l * 2304, qkv, 8192, 2304, 768);
    attn_kernel<<<768, 256, 0, stream>>>(qkv, mask, abf);
    // ao: 8192x768 K=768 -> BN=64 grid 768, bf16 residual RMW
    gemm_bt<1, 64><<<768, 256, 0, stream>>>(abf, waT + (long)l * 768 * 768,
                                            ao_b + l * 768, h, 8192, 768, 768);
    ln_kernel<true><<<2048, 256, 0, stream>>>(h, ln2_g + l * 768, ln2_b + l * 768, xb, nullptr);
    // fc: 8192x3072 K=768 -> 256x128 tile, grid 32*24 = 768 (exactly 3/CU)
    gemm_bw<3><<<768, 512, 0, stream>>>(xb, wfT + (long)l * 3072 * 768,
                                        fc_b + l * 3072, fb, 8192, 3072, 768);
    // op: 8192x768 K=3072 -> BN=64 grid 768, bf16 residual RMW
    gemm_bt<1, 64><<<768, 256, 0, stream>>>(fb, woT + (long)l * 768 * 3072,
                                            op_b + l * 768, h, 8192, 768, 3072);
  }

  ln_kernel<false><<<2048, 256, 0, stream>>>(h, lnf_g, lnf_b, nullptr, (float*)d_out);
}

// Round 17
// 1578.733 us; speedup vs baseline: 1.4638x; 1.0131x over previous
//
#include <hip/hip_runtime.h>
#include <hip/hip_bf16.h>

typedef __bf16 bf16_t;
typedef __bf16 bf16x8 __attribute__((ext_vector_type(8)));
typedef __bf16 bf16x4 __attribute__((ext_vector_type(4)));
typedef float  f32x4  __attribute__((ext_vector_type(4)));

#define DEV __device__ __forceinline__

DEV void gload_lds16(const void* g, void* l) {
  __builtin_amdgcn_global_load_lds(
      (__attribute__((address_space(1))) void*)(void*)g,
      (__attribute__((address_space(3))) void*)l, 16, 0, 0);
}

// ---------------- weight transpose+cast (batched over layers via z):
// in fp32 [L][K][N] -> out bf16 [L][N][K]. float4 reads, bf16x4 writes.
__global__ __launch_bounds__(256)
void transpose_cast(const float* __restrict__ in, bf16_t* __restrict__ out,
                    int K, int N) {
  __shared__ float tile[32][33];
  const long z = blockIdx.z;
  const float* inz = in + z * (long)K * N;
  bf16_t* outz = out + z * (long)N * K;
  const int k0 = blockIdx.x * 32;
  const int n0 = blockIdx.y * 32;
  const int tx = threadIdx.x & 7;        // n-chunk (x4)
  const int ty = threadIdx.x >> 3;       // 0..31
  const f32x4 ld = *(const f32x4*)&inz[(long)(k0 + ty) * N + n0 + tx * 4];
#pragma unroll
  for (int j = 0; j < 4; ++j) tile[ty][tx * 4 + j] = ld[j];
  __syncthreads();
  bf16x4 st;
#pragma unroll
  for (int j = 0; j < 4; ++j) st[j] = (bf16_t)tile[tx * 4 + j][ty];
  *(bf16x4*)&outz[(long)(n0 + ty) * K + k0 + tx * 4] = st;
}

// ---------------- embedding: h = wte[ids] + wpe[s]  (bf16 out, 8/thread)
__global__ __launch_bounds__(256)
void embed_kernel(const int* __restrict__ ids, const float* __restrict__ wte,
                  const float* __restrict__ wpe, bf16_t* __restrict__ h) {
  const int t = blockIdx.x * 256 + threadIdx.x;     // < 8192*96
  const int row = t / 96;
  const int c8  = (t % 96) * 8;
  const int s   = row & 1023;
  const float* wr = wte + (long)ids[row] * 768 + c8;
  const float* pr = wpe + (long)s * 768 + c8;
  bf16x8 o;
#pragma unroll
  for (int j = 0; j < 8; ++j) o[j] = (bf16_t)(wr[j] + pr[j]);
  *(bf16x8*)&h[(long)row * 768 + c8] = o;
}

// ---------------- layernorm: wave per row, 4 rows/block, vector loads,
// wave-only shfl reduction. x bf16; out bf16 (ob) or f32 (of).
template <bool BF16OUT>
__global__ __launch_bounds__(256)
void ln_kernel(const bf16_t* __restrict__ x, const float* __restrict__ g,
               const float* __restrict__ b, bf16_t* __restrict__ ob,
               float* __restrict__ of) {
  const int lane = threadIdx.x & 63;
  const long row = blockIdx.x * 4 + (threadIdx.x >> 6);
  const bf16_t* xr = x + row * 768;
  const bf16x8 v8 = *(const bf16x8*)&xr[lane * 8];          // cols [0,512)
  const bf16x4 v4 = *(const bf16x4*)&xr[512 + lane * 4];    // cols [512,768)
  float vv[12];
#pragma unroll
  for (int j = 0; j < 8; ++j) vv[j] = (float)v8[j];
#pragma unroll
  for (int j = 0; j < 4; ++j) vv[8 + j] = (float)v4[j];
  float s = 0.f, sq = 0.f;
#pragma unroll
  for (int j = 0; j < 12; ++j) { s += vv[j]; sq += vv[j] * vv[j]; }
#pragma unroll
  for (int o = 32; o; o >>= 1) { s += __shfl_xor(s, o); sq += __shfl_xor(sq, o); }
  const float mean = s * (1.f / 768.f);
  const float rs = rsqrtf(sq * (1.f / 768.f) - mean * mean + 1e-5f);
  if (BF16OUT) {
    bf16x8 o8; bf16x4 o4;
#pragma unroll
    for (int j = 0; j < 8; ++j) {
      const int col = lane * 8 + j;
      o8[j] = (bf16_t)((vv[j] - mean) * rs * g[col] + b[col]);
    }
#pragma unroll
    for (int j = 0; j < 4; ++j) {
      const int col = 512 + lane * 4 + j;
      o4[j] = (bf16_t)((vv[8 + j] - mean) * rs * g[col] + b[col]);
    }
    *(bf16x8*)&ob[row * 768 + lane * 8] = o8;
    *(bf16x4*)&ob[row * 768 + 512 + lane * 4] = o4;
  } else {
#pragma unroll
    for (int j = 0; j < 8; ++j) {
      const int col = lane * 8 + j;
      of[row * 768 + col] = (vv[j] - mean) * rs * g[col] + b[col];
    }
#pragma unroll
    for (int j = 0; j < 4; ++j) {
      const int col = 512 + lane * 4 + j;
      of[row * 768 + col] = (vv[8 + j] - mean) * rs * g[col] + b[col];
    }
  }
}

// ---------------- narrow GEMM (ao/op): BM=128, BN=64, BK=128, 256 thr,
// single-buffered 48 KB LDS. Grid 768 = 3 blocks/CU either way (vs BK=64's
// LDS-allowed 4), so residency is unchanged while barrier-drain events per
// FLOP halve (op: 48 -> 24 K-tiles). 16-slot XOR swizzle (slot^(row&15)):
// per 16-lane group bank-position covers all 8 x2 = 2-way = free.
// Fragments loaded per-ks (4A+2B b128 live) to stay ~80 VGPR at (256,4).
// EPI: 1 = bf16 residual RMW, 2 = bf16 store, 3 = gelu->bf16.
template <int EPI, int BN>
__global__ __launch_bounds__(256, 4)
void gemm_bt(const bf16_t* __restrict__ A, const bf16_t* __restrict__ Bt,
             const float* __restrict__ bias, bf16_t* __restrict__ Cb,
             int M, int N, int K) {
  constexpr int NI = BN / 32;            // n-fragments per wave
  __shared__ bf16_t As[128 * 128];       // 32 KB
  __shared__ bf16_t Bs[BN * 128];        // 16 KB (BN=64)
  const int tid  = threadIdx.x;
  const int lane = tid & 63, w = tid >> 6;
  const int col = lane & 15, s16 = lane >> 4;
  const int nbn = N / BN;
  const int cpx = gridDim.x >> 3;
  const int bid = (blockIdx.x & 7) * cpx + (blockIdx.x >> 3);
  const int bm = bid / nbn, bn = bid % nbn;
  const int wr = w >> 1, wc = w & 1;

  f32x4 acc[4][NI];
#pragma unroll
  for (int i = 0; i < 4; ++i)
#pragma unroll
    for (int j = 0; j < NI; ++j) acc[i][j] = f32x4{0.f, 0.f, 0.f, 0.f};

  const long arow0 = (long)bm * 128;
  const long brow0 = (long)bn * BN;

  const int nt = K >> 7;                 // BK=128
  for (int t = 0; t < nt; ++t) {
    const int k0 = t << 7;
    // A: 128 rows x 16 slots = 2048 -> 8 rounds of 256 x 16B
#pragma unroll
    for (int i = 0; i < 8; ++i) {
      const int c = i * 256 + tid;
      const int row = c >> 4, slot = c & 15;
      gload_lds16(A + (arow0 + row) * (long)K + k0 + ((slot ^ (row & 15)) << 3),
                  (char*)As + c * 16);
    }
    // B: BN rows x 16 slots -> BN/16 rounds
#pragma unroll
    for (int i = 0; i < BN / 16; ++i) {
      const int c = i * 256 + tid;
      const int row = c >> 4, slot = c & 15;
      gload_lds16(Bt + (brow0 + row) * (long)K + k0 + ((slot ^ (row & 15)) << 3),
                  (char*)Bs + c * 16);
    }
    __syncthreads();        // drains vmcnt(0): tile staged

#pragma unroll
    for (int ks = 0; ks < 4; ++ks) {     // 4 k-steps of 32
      const int slot = ks * 4 + s16;
      bf16x8 af[4], bfr[NI];
#pragma unroll
      for (int mi = 0; mi < 4; ++mi) {
        const int row = wr * 64 + mi * 16 + col;
        af[mi] = *(const bf16x8*)((char*)As + row * 256 +
                                  ((slot ^ (row & 15)) << 4));
      }
#pragma unroll
      for (int ni = 0; ni < NI; ++ni) {
        const int row = wc * (BN / 2) + ni * 16 + col;
        bfr[ni] = *(const bf16x8*)((char*)Bs + row * 256 +
                                   ((slot ^ (row & 15)) << 4));
      }
#pragma unroll
      for (int mi = 0; mi < 4; ++mi)
#pragma unroll
        for (int ni = 0; ni < NI; ++ni)
          acc[mi][ni] = __builtin_amdgcn_mfma_f32_16x16x32_bf16(
              af[mi], bfr[ni], acc[mi][ni], 0, 0, 0);
    }

    __syncthreads();        // all reads done before next stage overwrites
  }

  const int colb = bn * BN + wc * (BN / 2) + col;
  const int rowb = bm * 128 + wr * 64 + (s16 << 2);
#pragma unroll
  for (int ni = 0; ni < NI; ++ni) {
    const int ccol = colb + ni * 16;
    const float bv = bias[ccol];
#pragma unroll
    for (int mi = 0; mi < 4; ++mi) {
      const int row = rowb + mi * 16;
#pragma unroll
      for (int r = 0; r < 4; ++r) {
        const float v = acc[mi][ni][r] + bv;
        const long idx = (long)(row + r) * N + ccol;
        if (EPI == 1) {
          Cb[idx] = (bf16_t)((float)Cb[idx] + v);    // bf16 residual RMW
        } else if (EPI == 2) {
          Cb[idx] = (bf16_t)v;
        } else {
          const float z = 0.7978845608028654f * (v + 0.044715f * v * v * v);
          Cb[idx] = (bf16_t)(v / (1.f + __expf(-2.f * z)));
        }
      }
    }
  }
}

// ---------------- big GEMM (qkv/fc): BM=256, BN=128, BK=64, 512 thr =
// 8 waves (4M x 2N, 64x64 out each), single-buffered 48 KB LDS (R13-proven).
// EPI: 2 bf16 store, 3 gelu->bf16.
template <int EPI>
__global__ __launch_bounds__(512, 4)
void gemm_bw(const bf16_t* __restrict__ A, const bf16_t* __restrict__ Bt,
             const float* __restrict__ bias, bf16_t* __restrict__ Cb,
             int M, int N, int K) {
  __shared__ bf16_t As[256 * 64];   // 32 KB
  __shared__ bf16_t Bs[128 * 64];   // 16 KB
  const int tid = threadIdx.x;
  const int lane = tid & 63, w = tid >> 6;
  const int col = lane & 15, s16 = lane >> 4;
  const int wm = w >> 1, wn = w & 1;        // 4M x 2N waves, 64x64 each
  const int nbn = N >> 7;
  const int cpx = gridDim.x >> 3;
  const int bid = (blockIdx.x & 7) * cpx + (blockIdx.x >> 3);
  const int bm = bid / nbn, bn = bid % nbn;
  const long arow0 = (long)bm * 256, brow0 = (long)bn * 128;

  f32x4 acc[4][4];
#pragma unroll
  for (int i = 0; i < 4; ++i)
#pragma unroll
    for (int j = 0; j < 4; ++j) acc[i][j] = f32x4{0.f, 0.f, 0.f, 0.f};

  const int nt = K >> 6;
  for (int t = 0; t < nt; ++t) {
    const int k0 = t << 6;
#pragma unroll
    for (int i = 0; i < 4; ++i) {           // A: 256 rows = 2048 slots
      const int c = i * 512 + tid;
      const int row = c >> 3, slot = c & 7;
      gload_lds16(A + (arow0 + row) * (long)K + k0 + ((slot ^ (row & 7)) << 3),
                  (char*)As + c * 16);
    }
#pragma unroll
    for (int i = 0; i < 2; ++i) {           // B: 128 rows = 1024 slots
      const int c = i * 512 + tid;
      const int row = c >> 3, slot = c & 7;
      gload_lds16(Bt + (brow0 + row) * (long)K + k0 + ((slot ^ (row & 7)) << 3),
                  (char*)Bs + c * 16);
    }
    __syncthreads();        // drains vmcnt(0): tile staged

    bf16x8 af[2][4], bfr[2][4];
#pragma unroll
    for (int mi = 0; mi < 4; ++mi) {
      const int row = wm * 64 + mi * 16 + col;
#pragma unroll
      for (int ks = 0; ks < 2; ++ks) {
        const int slot = ks * 4 + s16;
        af[ks][mi] = *(const bf16x8*)((char*)As + row * 128 +
                                      ((slot ^ (row & 7)) << 4));
      }
    }
#pragma unroll
    for (int ni = 0; ni < 4; ++ni) {
      const int row = wn * 64 + ni * 16 + col;
#pragma unroll
      for (int ks = 0; ks < 2; ++ks) {
        const int slot = ks * 4 + s16;
        bfr[ks][ni] = *(const bf16x8*)((char*)Bs + row * 128 +
                                       ((slot ^ (row & 7)) << 4));
      }
    }
#pragma unroll
    for (int ks = 0; ks < 2; ++ks)
#pragma unroll
      for (int mi = 0; mi < 4; ++mi)
#pragma unroll
        for (int ni = 0; ni < 4; ++ni)
          acc[mi][ni] = __builtin_amdgcn_mfma_f32_16x16x32_bf16(
              af[ks][mi], bfr[ks][ni], acc[mi][ni], 0, 0, 0);

    __syncthreads();
  }

  const int rowb = bm * 256 + wm * 64 + (s16 << 2);
  const int colb = bn * 128 + wn * 64 + col;
#pragma unroll
  for (int ni = 0; ni < 4; ++ni) {
    const int ccol = colb + ni * 16;
    const float bv = bias[ccol];
#pragma unroll
    for (int mi = 0; mi < 4; ++mi) {
      const int row = rowb + mi * 16;
#pragma unroll
      for (int r = 0; r < 4; ++r) {
        const float v = acc[mi][ni][r] + bv;
        if (EPI == 2) Cb[(long)(row + r) * N + ccol] = (bf16_t)v;
        else {
          const float z = 0.7978845608028654f * (v + 0.044715f * v * v * v);
          Cb[(long)(row + r) * N + ccol] = (bf16_t)(v / (1.f + __expf(-2.f * z)));
        }
      }
    }
  }
}

// ---------------- flash attention: paired q-tiles, double-buffered K/V,
// async-stage split (issue-early/write-late), one barrier per kt-iteration.
__global__ __launch_bounds__(256, 3)
void attn_kernel(const bf16_t* __restrict__ qkv, const float* __restrict__ mask,
                 bf16_t* __restrict__ out) {
  __shared__ bf16_t Kl[2][64 * 64];   // [key][dh], slot-swizzled
  __shared__ bf16_t Vt[2][64 * 64];   // [d][k],   slot-swizzled
  __shared__ bf16_t Pl[4][16 * 64];   // per-wave [q][key], slot-swizzled
  const int tid = threadIdx.x, lane = tid & 63, w = tid >> 6;
  const int col = lane & 15, s16 = lane >> 4, l7 = lane & 7;
  const int qp = blockIdx.x & 7;      // pair id: handles qt = qp and 15-qp
  const int bh = blockIdx.x >> 3;     // 0..95
  const int b = bh / 12, h = bh % 12;
  const int sw0 = (s16 ^ l7) << 4;
  const int sw1 = ((s16 + 4) ^ l7) << 4;
  char* const plw = (char*)&Pl[w][0];
  const long qkvb = (long)b * 1024 * 2304;

  auto stageK = [&](int buf, int k0) {
#pragma unroll
    for (int i = 0; i < 2; ++i) {
      const int c = i * 256 + tid;
      const int krow = c >> 3, slot = c & 7;
      gload_lds16(qkv + qkvb + (long)(k0 + krow) * 2304 + 768 + h * 64 +
                      ((slot ^ (krow & 7)) << 3),
                  (char*)&Kl[buf][0] + i * 4096 + w * 1024);
    }
  };
  auto loadV = [&](int k0, bf16x8& t0, bf16x8& t1) {
    const bf16_t* vbase = qkv + qkvb + 1536 + h * 64;
#pragma unroll
    for (int i = 0; i < 2; ++i) {
      const int c = i * 256 + tid;
      const int d = c & 63, koct = c >> 6;
      const bf16_t* vsrc = vbase + (long)(k0 + koct * 8) * 2304 + d;
      bf16x8 tv;
#pragma unroll
      for (int j = 0; j < 8; ++j) tv[j] = vsrc[(long)j * 2304];
      if (i == 0) t0 = tv; else t1 = tv;
    }
  };
  auto storeV = [&](int buf, const bf16x8& t0, const bf16x8& t1) {
#pragma unroll
    for (int i = 0; i < 2; ++i) {
      const int c = i * 256 + tid;
      const int d = c & 63, koct = c >> 6;
      *(bf16x8*)((char*)&Vt[buf][0] + d * 128 + ((koct ^ (d & 7)) << 4)) =
          (i == 0) ? t0 : t1;
    }
  };

#pragma unroll 1
  for (int pass = 0; pass < 2; ++pass) {
    const int qt = pass ? (15 - qp) : qp;
    const int qrow0 = qt * 64 + w * 16;
    const long rowQ = (long)(b * 1024 + qrow0 + col) * 2304 + h * 64;
    const bf16x8 aq0 = *(const bf16x8*)&qkv[rowQ + s16 * 8];
    const bf16x8 aq1 = *(const bf16x8*)&qkv[rowQ + 32 + s16 * 8];
    const int qb = qrow0 + s16 * 4;
    const float* mrow = mask + ((long)b * 1024 + qb) * 1024;

    auto loadM = [&](int k0, float (&m)[4][4]) {
#pragma unroll
      for (int g = 0; g < 4; ++g)
#pragma unroll
        for (int r = 0; r < 4; ++r)
          m[g][r] = mrow[(long)r * 1024 + k0 + g * 16 + col];
    };

    float m_run[4], l_run[4];
    f32x4 o_acc[4];
#pragma unroll
    for (int r = 0; r < 4; ++r) { m_run[r] = -INFINITY; l_run[r] = 0.f; }
#pragma unroll
    for (int go = 0; go < 4; ++go) o_acc[go] = f32x4{0.f, 0.f, 0.f, 0.f};

    bf16x8 tv0, tv1;
    stageK(0, 0);
    loadV(0, tv0, tv1);
    storeV(0, tv0, tv1);
    float msk[4][4];
    loadM(0, msk);
    __syncthreads();

#pragma unroll 1
    for (int kt = 0; kt <= qt; ++kt) {
      const int cur = kt & 1;
      const bool more = kt < qt;
      const int k0 = kt * 64;
      float mnx[4][4];
      if (more) {
        stageK(cur ^ 1, k0 + 64);
        loadV(k0 + 64, tv0, tv1);
        loadM(k0 + 64, mnx);
      }

      f32x4 sf[4];
      __builtin_amdgcn_s_setprio(1);
#pragma unroll
      for (int g = 0; g < 4; ++g) {
        const int rbyte = (g * 16 + col) * 128;
        bf16x8 bk0 = *(const bf16x8*)((char*)&Kl[cur][0] + rbyte + sw0);
        bf16x8 bk1 = *(const bf16x8*)((char*)&Kl[cur][0] + rbyte + sw1);
        f32x4 z = f32x4{0.f, 0.f, 0.f, 0.f};
        z = __builtin_amdgcn_mfma_f32_16x16x32_bf16(aq0, bk0, z, 0, 0, 0);
        z = __builtin_amdgcn_mfma_f32_16x16x32_bf16(aq1, bk1, z, 0, 0, 0);
        sf[g] = z;
      }
      __builtin_amdgcn_s_setprio(0);

      const bool diag = (kt == qt);
      float sv[4][4];
#pragma unroll
      for (int g = 0; g < 4; ++g)
#pragma unroll
        for (int r = 0; r < 4; ++r) {
          float s = sf[g][r] * 0.125f + msk[g][r];
          if (diag && (k0 + g * 16 + col) > (qb + r)) s = -INFINITY;
          sv[g][r] = s;
        }
#pragma unroll
      for (int r = 0; r < 4; ++r) {
        float mx = fmaxf(fmaxf(sv[0][r], sv[1][r]), fmaxf(sv[2][r], sv[3][r]));
#pragma unroll
        for (int o = 8; o; o >>= 1) mx = fmaxf(mx, __shfl_xor(mx, o));
        const float m_new = fmaxf(m_run[r], mx);
        const float f = __expf(m_run[r] - m_new);
        m_run[r] = m_new;
        float sum = 0.f;
#pragma unroll
        for (int g = 0; g < 4; ++g) {
          const float p = __expf(sv[g][r] - m_new);
          sv[g][r] = p;
          sum += p;
        }
#pragma unroll
        for (int o = 8; o; o >>= 1) sum += __shfl_xor(sum, o);
        l_run[r] = l_run[r] * f + sum;
#pragma unroll
        for (int go = 0; go < 4; ++go) o_acc[go][r] *= f;
      }

#pragma unroll
      for (int g = 0; g < 4; ++g) {
        const int ks = 2 * g + (col >> 3);
#pragma unroll
        for (int r = 0; r < 4; ++r) {
          const int qr = s16 * 4 + r;
          *(bf16_t*)(plw + qr * 128 + ((ks ^ (qr & 7)) << 4) + l7 * 2) = (bf16_t)sv[g][r];
        }
      }
      const bf16x8 pa0 = *(const bf16x8*)(plw + col * 128 + sw0);
      const bf16x8 pa1 = *(const bf16x8*)(plw + col * 128 + sw1);
      __builtin_amdgcn_s_setprio(1);
#pragma unroll
      for (int go = 0; go < 4; ++go) {
        const int dbyte = (go * 16 + col) * 128;
        bf16x8 bv0 = *(const bf16x8*)((char*)&Vt[cur][0] + dbyte + sw0);
        bf16x8 bv1 = *(const bf16x8*)((char*)&Vt[cur][0] + dbyte + sw1);
        o_acc[go] = __builtin_amdgcn_mfma_f32_16x16x32_bf16(pa0, bv0, o_acc[go], 0, 0, 0);
        o_acc[go] = __builtin_amdgcn_mfma_f32_16x16x32_bf16(pa1, bv1, o_acc[go], 0, 0, 0);
      }
      __builtin_amdgcn_s_setprio(0);

      if (more) {
        storeV(cur ^ 1, tv0, tv1);
#pragma unroll
        for (int g = 0; g < 4; ++g)
#pragma unroll
          for (int r = 0; r < 4; ++r) msk[g][r] = mnx[g][r];
      }
      __syncthreads();
    }

    float inv[4];
#pragma unroll
    for (int r = 0; r < 4; ++r) inv[r] = 1.f / l_run[r];
#pragma unroll
    for (int go = 0; go < 4; ++go)
#pragma unroll
      for (int r = 0; r < 4; ++r)
        out[(long)(b * 1024 + qb + r) * 768 + h * 64 + go * 16 + col] =
            (bf16_t)(o_acc[go][r] * inv[r]);
  }
}

// ---------------- host
extern "C" void kernel_launch(void* const* d_in, const int* in_sizes, int n_in,
                              void* d_out, int out_size, void* d_ws, size_t ws_size,
                              hipStream_t stream) {
  const int*   x_ids = (const int*)d_in[0];
  const float* mask  = (const float*)d_in[1];
  const float* wte   = (const float*)d_in[2];
  const float* wpe   = (const float*)d_in[3];
  const float* ln1_g = (const float*)d_in[4];
  const float* ln1_b = (const float*)d_in[5];
  const float* qkv_w = (const float*)d_in[6];
  const float* qkv_b = (const float*)d_in[7];
  const float* ao_w  = (const float*)d_in[8];
  const float* ao_b  = (const float*)d_in[9];
  const float* ln2_g = (const float*)d_in[10];
  const float* ln2_b = (const float*)d_in[11];
  const float* fc_w  = (const float*)d_in[12];
  const float* fc_b  = (const float*)d_in[13];
  const float* op_w  = (const float*)d_in[14];
  const float* op_b  = (const float*)d_in[15];
  const float* lnf_g = (const float*)d_in[16];
  const float* lnf_b = (const float*)d_in[17];

  char* ws = (char*)d_ws;
  size_t off = 0;
  auto alloc = [&](size_t bytes) {
    char* p = ws + off;
    off += (bytes + 255) & ~(size_t)255;
    return p;
  };
  bf16_t* wqT = (bf16_t*)alloc(6ull * 2304 * 768 * 2);
  bf16_t* waT = (bf16_t*)alloc(6ull * 768 * 768 * 2);
  bf16_t* wfT = (bf16_t*)alloc(6ull * 3072 * 768 * 2);
  bf16_t* woT = (bf16_t*)alloc(6ull * 768 * 3072 * 2);
  bf16_t* h   = (bf16_t*)alloc(8192ull * 768 * 2);     // residual stream, bf16
  bf16_t* xb  = (bf16_t*)alloc(8192ull * 768 * 2);
  bf16_t* qkv = (bf16_t*)alloc(8192ull * 2304 * 2);
  bf16_t* abf = (bf16_t*)alloc(8192ull * 768 * 2);
  bf16_t* fb  = (bf16_t*)alloc(8192ull * 3072 * 2);
  if (off > ws_size) return;

  // batched transposes: one launch per weight class (z = layer)
  transpose_cast<<<dim3(768 / 32, 2304 / 32, 6), 256, 0, stream>>>(qkv_w, wqT, 768, 2304);
  transpose_cast<<<dim3(768 / 32, 768 / 32, 6), 256, 0, stream>>>(ao_w, waT, 768, 768);
  transpose_cast<<<dim3(768 / 32, 3072 / 32, 6), 256, 0, stream>>>(fc_w, wfT, 768, 3072);
  transpose_cast<<<dim3(3072 / 32, 768 / 32, 6), 256, 0, stream>>>(op_w, woT, 3072, 768);

  embed_kernel<<<3072, 256, 0, stream>>>(x_ids, wte, wpe, h);

  for (int l = 0; l < 6; ++l) {
    ln_kernel<true><<<2048, 256, 0, stream>>>(h, ln1_g + l * 768, ln1_b + l * 768, xb, nullptr);
    // qkv: 8192x2304 K=768 -> 256x128 tile, grid 32*18 = 576
    gemm_bw<2><<<576, 512, 0, stream>>>(xb, wqT + (long)l * 2304 * 768,
                                        qkv_b + l * 2304, qkv, 8192, 2304, 768);
    attn_kernel<<<768, 256, 0, stream>>>(qkv, mask, abf);
    // ao: 8192x768 K=768 -> BN=64 BK=128 grid 768, bf16 residual RMW
    gemm_bt<1, 64><<<768, 256, 0, stream>>>(abf, waT + (long)l * 768 * 768,
                                            ao_b + l * 768, h, 8192, 768, 768);
    ln_kernel<true><<<2048, 256, 0, stream>>>(h, ln2_g + l * 768, ln2_b + l * 768, xb, nullptr);
    // fc: 8192x3072 K=768 -> 256x128 tile, grid 32*24 = 768 (exactly 3/CU)
    gemm_bw<3><<<768, 512, 0, stream>>>(xb, wfT + (long)l * 3072 * 768,
                                        fc_b + l * 3072, fb, 8192, 3072, 768);
    // op: 8192x768 K=3072 -> BN=64 BK=128 grid 768, bf16 residual RMW
    gemm_bt<1, 64><<<768, 256, 0, stream>>>(fb, woT + (long)l * 768 * 3072,
                                            op_b + l * 768, h, 8192, 768, 3072);
  }

  ln_kernel<false><<<2048, 256, 0, stream>>>(h, lnf_g, lnf_b, nullptr, (float*)d_out);
}

// Round 18
// 1578.439 us; speedup vs baseline: 1.4641x; 1.0002x over previous
//
#include <hip/hip_runtime.h>
#include <hip/hip_bf16.h>

typedef __bf16 bf16_t;
typedef __bf16 bf16x8 __attribute__((ext_vector_type(8)));
typedef __bf16 bf16x4 __attribute__((ext_vector_type(4)));
typedef float  f32x4  __attribute__((ext_vector_type(4)));

#define DEV __device__ __forceinline__

DEV void gload_lds16(const void* g, void* l) {
  __builtin_amdgcn_global_load_lds(
      (__attribute__((address_space(1))) void*)(void*)g,
      (__attribute__((address_space(3))) void*)l, 16, 0, 0);
}

// ---------------- weight transpose+cast (batched over layers via z):
// in fp32 [L][K][N] -> out bf16 [L][N][K]. float4 reads, bf16x4 writes.
__global__ __launch_bounds__(256)
void transpose_cast(const float* __restrict__ in, bf16_t* __restrict__ out,
                    int K, int N) {
  __shared__ float tile[32][33];
  const long z = blockIdx.z;
  const float* inz = in + z * (long)K * N;
  bf16_t* outz = out + z * (long)N * K;
  const int k0 = blockIdx.x * 32;
  const int n0 = blockIdx.y * 32;
  const int tx = threadIdx.x & 7;        // n-chunk (x4)
  const int ty = threadIdx.x >> 3;       // 0..31
  const f32x4 ld = *(const f32x4*)&inz[(long)(k0 + ty) * N + n0 + tx * 4];
#pragma unroll
  for (int j = 0; j < 4; ++j) tile[ty][tx * 4 + j] = ld[j];
  __syncthreads();
  bf16x4 st;
#pragma unroll
  for (int j = 0; j < 4; ++j) st[j] = (bf16_t)tile[tx * 4 + j][ty];
  *(bf16x4*)&outz[(long)(n0 + ty) * K + k0 + tx * 4] = st;
}

// ---------------- embedding: h = wte[ids] + wpe[s]  (bf16 out, 8/thread)
__global__ __launch_bounds__(256)
void embed_kernel(const int* __restrict__ ids, const float* __restrict__ wte,
                  const float* __restrict__ wpe, bf16_t* __restrict__ h) {
  const int t = blockIdx.x * 256 + threadIdx.x;     // < 8192*96
  const int row = t / 96;
  const int c8  = (t % 96) * 8;
  const int s   = row & 1023;
  const float* wr = wte + (long)ids[row] * 768 + c8;
  const float* pr = wpe + (long)s * 768 + c8;
  bf16x8 o;
#pragma unroll
  for (int j = 0; j < 8; ++j) o[j] = (bf16_t)(wr[j] + pr[j]);
  *(bf16x8*)&h[(long)row * 768 + c8] = o;
}

// ---------------- layernorm: wave per row, 4 rows/block, vector loads,
// wave-only shfl reduction. x bf16; out bf16 (ob) or f32 (of).
template <bool BF16OUT>
__global__ __launch_bounds__(256)
void ln_kernel(const bf16_t* __restrict__ x, const float* __restrict__ g,
               const float* __restrict__ b, bf16_t* __restrict__ ob,
               float* __restrict__ of) {
  const int lane = threadIdx.x & 63;
  const long row = blockIdx.x * 4 + (threadIdx.x >> 6);
  const bf16_t* xr = x + row * 768;
  const bf16x8 v8 = *(const bf16x8*)&xr[lane * 8];          // cols [0,512)
  const bf16x4 v4 = *(const bf16x4*)&xr[512 + lane * 4];    // cols [512,768)
  float vv[12];
#pragma unroll
  for (int j = 0; j < 8; ++j) vv[j] = (float)v8[j];
#pragma unroll
  for (int j = 0; j < 4; ++j) vv[8 + j] = (float)v4[j];
  float s = 0.f, sq = 0.f;
#pragma unroll
  for (int j = 0; j < 12; ++j) { s += vv[j]; sq += vv[j] * vv[j]; }
#pragma unroll
  for (int o = 32; o; o >>= 1) { s += __shfl_xor(s, o); sq += __shfl_xor(sq, o); }
  const float mean = s * (1.f / 768.f);
  const float rs = rsqrtf(sq * (1.f / 768.f) - mean * mean + 1e-5f);
  if (BF16OUT) {
    bf16x8 o8; bf16x4 o4;
#pragma unroll
    for (int j = 0; j < 8; ++j) {
      const int col = lane * 8 + j;
      o8[j] = (bf16_t)((vv[j] - mean) * rs * g[col] + b[col]);
    }
#pragma unroll
    for (int j = 0; j < 4; ++j) {
      const int col = 512 + lane * 4 + j;
      o4[j] = (bf16_t)((vv[8 + j] - mean) * rs * g[col] + b[col]);
    }
    *(bf16x8*)&ob[row * 768 + lane * 8] = o8;
    *(bf16x4*)&ob[row * 768 + 512 + lane * 4] = o4;
  } else {
#pragma unroll
    for (int j = 0; j < 8; ++j) {
      const int col = lane * 8 + j;
      of[row * 768 + col] = (vv[j] - mean) * rs * g[col] + b[col];
    }
#pragma unroll
    for (int j = 0; j < 4; ++j) {
      const int col = 512 + lane * 4 + j;
      of[row * 768 + col] = (vv[8 + j] - mean) * rs * g[col] + b[col];
    }
  }
}

// ---------------- narrow GEMM (ao/op): BM=128, BN=64, BK=128, 256 thr,
// single-buffered 48 KB LDS (3 blocks/CU, grid 768 = exact). 16-slot XOR
// swizzle. R17-proven (+21 us vs BK=64).
// EPI: 1 = bf16 residual RMW, 2 = bf16 store, 3 = gelu->bf16.
template <int EPI, int BN>
__global__ __launch_bounds__(256, 4)
void gemm_bt(const bf16_t* __restrict__ A, const bf16_t* __restrict__ Bt,
             const float* __restrict__ bias, bf16_t* __restrict__ Cb,
             int M, int N, int K) {
  constexpr int NI = BN / 32;            // n-fragments per wave
  __shared__ bf16_t As[128 * 128];       // 32 KB
  __shared__ bf16_t Bs[BN * 128];        // 16 KB (BN=64)
  const int tid  = threadIdx.x;
  const int lane = tid & 63, w = tid >> 6;
  const int col = lane & 15, s16 = lane >> 4;
  const int nbn = N / BN;
  const int cpx = gridDim.x >> 3;
  const int bid = (blockIdx.x & 7) * cpx + (blockIdx.x >> 3);
  const int bm = bid / nbn, bn = bid % nbn;
  const int wr = w >> 1, wc = w & 1;

  f32x4 acc[4][NI];
#pragma unroll
  for (int i = 0; i < 4; ++i)
#pragma unroll
    for (int j = 0; j < NI; ++j) acc[i][j] = f32x4{0.f, 0.f, 0.f, 0.f};

  const long arow0 = (long)bm * 128;
  const long brow0 = (long)bn * BN;

  const int nt = K >> 7;                 // BK=128
  for (int t = 0; t < nt; ++t) {
    const int k0 = t << 7;
#pragma unroll
    for (int i = 0; i < 8; ++i) {
      const int c = i * 256 + tid;
      const int row = c >> 4, slot = c & 15;
      gload_lds16(A + (arow0 + row) * (long)K + k0 + ((slot ^ (row & 15)) << 3),
                  (char*)As + c * 16);
    }
#pragma unroll
    for (int i = 0; i < BN / 16; ++i) {
      const int c = i * 256 + tid;
      const int row = c >> 4, slot = c & 15;
      gload_lds16(Bt + (brow0 + row) * (long)K + k0 + ((slot ^ (row & 15)) << 3),
                  (char*)Bs + c * 16);
    }
    __syncthreads();        // drains vmcnt(0): tile staged

#pragma unroll
    for (int ks = 0; ks < 4; ++ks) {     // 4 k-steps of 32
      const int slot = ks * 4 + s16;
      bf16x8 af[4], bfr[NI];
#pragma unroll
      for (int mi = 0; mi < 4; ++mi) {
        const int row = wr * 64 + mi * 16 + col;
        af[mi] = *(const bf16x8*)((char*)As + row * 256 +
                                  ((slot ^ (row & 15)) << 4));
      }
#pragma unroll
      for (int ni = 0; ni < NI; ++ni) {
        const int row = wc * (BN / 2) + ni * 16 + col;
        bfr[ni] = *(const bf16x8*)((char*)Bs + row * 256 +
                                   ((slot ^ (row & 15)) << 4));
      }
#pragma unroll
      for (int mi = 0; mi < 4; ++mi)
#pragma unroll
        for (int ni = 0; ni < NI; ++ni)
          acc[mi][ni] = __builtin_amdgcn_mfma_f32_16x16x32_bf16(
              af[mi], bfr[ni], acc[mi][ni], 0, 0, 0);
    }

    __syncthreads();        // all reads done before next stage overwrites
  }

  const int colb = bn * BN + wc * (BN / 2) + col;
  const int rowb = bm * 128 + wr * 64 + (s16 << 2);
#pragma unroll
  for (int ni = 0; ni < NI; ++ni) {
    const int ccol = colb + ni * 16;
    const float bv = bias[ccol];
#pragma unroll
    for (int mi = 0; mi < 4; ++mi) {
      const int row = rowb + mi * 16;
#pragma unroll
      for (int r = 0; r < 4; ++r) {
        const float v = acc[mi][ni][r] + bv;
        const long idx = (long)(row + r) * N + ccol;
        if (EPI == 1) {
          Cb[idx] = (bf16_t)((float)Cb[idx] + v);    // bf16 residual RMW
        } else if (EPI == 2) {
          Cb[idx] = (bf16_t)v;
        } else {
          const float z = 0.7978845608028654f * (v + 0.044715f * v * v * v);
          Cb[idx] = (bf16_t)(v / (1.f + __expf(-2.f * z)));
        }
      }
    }
  }
}

// ---------------- big GEMM (qkv/fc): BM=256, BN=128, BK=64, 512 thr =
// 8 waves (4M x 2N, 64x64 out each), single-buffered 48 KB LDS.
// __launch_bounds__(512) with NO min-waves arg: allocator keeps natural
// ~60 VGPR, occupancy cap becomes the LDS limit -> 3 blocks/CU (vs 2 at
// (512,4)). fc grid 768 = one full round of 3/CU; qkv 576 all-resident.
// EPI: 2 bf16 store, 3 gelu->bf16.
template <int EPI>
__global__ __launch_bounds__(512)
void gemm_bw(const bf16_t* __restrict__ A, const bf16_t* __restrict__ Bt,
             const float* __restrict__ bias, bf16_t* __restrict__ Cb,
             int M, int N, int K) {
  __shared__ bf16_t As[256 * 64];   // 32 KB
  __shared__ bf16_t Bs[128 * 64];   // 16 KB
  const int tid = threadIdx.x;
  const int lane = tid & 63, w = tid >> 6;
  const int col = lane & 15, s16 = lane >> 4;
  const int wm = w >> 1, wn = w & 1;        // 4M x 2N waves, 64x64 each
  const int nbn = N >> 7;
  const int cpx = gridDim.x >> 3;
  const int bid = (blockIdx.x & 7) * cpx + (blockIdx.x >> 3);
  const int bm = bid / nbn, bn = bid % nbn;
  const long arow0 = (long)bm * 256, brow0 = (long)bn * 128;

  f32x4 acc[4][4];
#pragma unroll
  for (int i = 0; i < 4; ++i)
#pragma unroll
    for (int j = 0; j < 4; ++j) acc[i][j] = f32x4{0.f, 0.f, 0.f, 0.f};

  const int nt = K >> 6;
  for (int t = 0; t < nt; ++t) {
    const int k0 = t << 6;
#pragma unroll
    for (int i = 0; i < 4; ++i) {           // A: 256 rows = 2048 slots
      const int c = i * 512 + tid;
      const int row = c >> 3, slot = c & 7;
      gload_lds16(A + (arow0 + row) * (long)K + k0 + ((slot ^ (row & 7)) << 3),
                  (char*)As + c * 16);
    }
#pragma unroll
    for (int i = 0; i < 2; ++i) {           // B: 128 rows = 1024 slots
      const int c = i * 512 + tid;
      const int row = c >> 3, slot = c & 7;
      gload_lds16(Bt + (brow0 + row) * (long)K + k0 + ((slot ^ (row & 7)) << 3),
                  (char*)Bs + c * 16);
    }
    __syncthreads();        // drains vmcnt(0): tile staged

    bf16x8 af[2][4], bfr[2][4];
#pragma unroll
    for (int mi = 0; mi < 4; ++mi) {
      const int row = wm * 64 + mi * 16 + col;
#pragma unroll
      for (int ks = 0; ks < 2; ++ks) {
        const int slot = ks * 4 + s16;
        af[ks][mi] = *(const bf16x8*)((char*)As + row * 128 +
                                      ((slot ^ (row & 7)) << 4));
      }
    }
#pragma unroll
    for (int ni = 0; ni < 4; ++ni) {
      const int row = wn * 64 + ni * 16 + col;
#pragma unroll
      for (int ks = 0; ks < 2; ++ks) {
        const int slot = ks * 4 + s16;
        bfr[ks][ni] = *(const bf16x8*)((char*)Bs + row * 128 +
                                       ((slot ^ (row & 7)) << 4));
      }
    }
#pragma unroll
    for (int ks = 0; ks < 2; ++ks)
#pragma unroll
      for (int mi = 0; mi < 4; ++mi)
#pragma unroll
        for (int ni = 0; ni < 4; ++ni)
          acc[mi][ni] = __builtin_amdgcn_mfma_f32_16x16x32_bf16(
              af[ks][mi], bfr[ks][ni], acc[mi][ni], 0, 0, 0);

    __syncthreads();
  }

  const int rowb = bm * 256 + wm * 64 + (s16 << 2);
  const int colb = bn * 128 + wn * 64 + col;
#pragma unroll
  for (int ni = 0; ni < 4; ++ni) {
    const int ccol = colb + ni * 16;
    const float bv = bias[ccol];
#pragma unroll
    for (int mi = 0; mi < 4; ++mi) {
      const int row = rowb + mi * 16;
#pragma unroll
      for (int r = 0; r < 4; ++r) {
        const float v = acc[mi][ni][r] + bv;
        if (EPI == 2) Cb[(long)(row + r) * N + ccol] = (bf16_t)v;
        else {
          const float z = 0.7978845608028654f * (v + 0.044715f * v * v * v);
          Cb[(long)(row + r) * N + ccol] = (bf16_t)(v / (1.f + __expf(-2.f * z)));
        }
      }
    }
  }
}

// ---------------- flash attention: paired q-tiles, double-buffered K/V,
// async-stage split (issue-early/write-late), one barrier per kt-iteration.
__global__ __launch_bounds__(256, 3)
void attn_kernel(const bf16_t* __restrict__ qkv, const float* __restrict__ mask,
                 bf16_t* __restrict__ out) {
  __shared__ bf16_t Kl[2][64 * 64];   // [key][dh], slot-swizzled
  __shared__ bf16_t Vt[2][64 * 64];   // [d][k],   slot-swizzled
  __shared__ bf16_t Pl[4][16 * 64];   // per-wave [q][key], slot-swizzled
  const int tid = threadIdx.x, lane = tid & 63, w = tid >> 6;
  const int col = lane & 15, s16 = lane >> 4, l7 = lane & 7;
  const int qp = blockIdx.x & 7;      // pair id: handles qt = qp and 15-qp
  const int bh = blockIdx.x >> 3;     // 0..95
  const int b = bh / 12, h = bh % 12;
  const int sw0 = (s16 ^ l7) << 4;
  const int sw1 = ((s16 + 4) ^ l7) << 4;
  char* const plw = (char*)&Pl[w][0];
  const long qkvb = (long)b * 1024 * 2304;

  auto stageK = [&](int buf, int k0) {
#pragma unroll
    for (int i = 0; i < 2; ++i) {
      const int c = i * 256 + tid;
      const int krow = c >> 3, slot = c & 7;
      gload_lds16(qkv + qkvb + (long)(k0 + krow) * 2304 + 768 + h * 64 +
                      ((slot ^ (krow & 7)) << 3),
                  (char*)&Kl[buf][0] + i * 4096 + w * 1024);
    }
  };
  auto loadV = [&](int k0, bf16x8& t0, bf16x8& t1) {
    const bf16_t* vbase = qkv + qkvb + 1536 + h * 64;
#pragma unroll
    for (int i = 0; i < 2; ++i) {
      const int c = i * 256 + tid;
      const int d = c & 63, koct = c >> 6;
      const bf16_t* vsrc = vbase + (long)(k0 + koct * 8) * 2304 + d;
      bf16x8 tv;
#pragma unroll
      for (int j = 0; j < 8; ++j) tv[j] = vsrc[(long)j * 2304];
      if (i == 0) t0 = tv; else t1 = tv;
    }
  };
  auto storeV = [&](int buf, const bf16x8& t0, const bf16x8& t1) {
#pragma unroll
    for (int i = 0; i < 2; ++i) {
      const int c = i * 256 + tid;
      const int d = c & 63, koct = c >> 6;
      *(bf16x8*)((char*)&Vt[buf][0] + d * 128 + ((koct ^ (d & 7)) << 4)) =
          (i == 0) ? t0 : t1;
    }
  };

#pragma unroll 1
  for (int pass = 0; pass < 2; ++pass) {
    const int qt = pass ? (15 - qp) : qp;
    const int qrow0 = qt * 64 + w * 16;
    const long rowQ = (long)(b * 1024 + qrow0 + col) * 2304 + h * 64;
    const bf16x8 aq0 = *(const bf16x8*)&qkv[rowQ + s16 * 8];
    const bf16x8 aq1 = *(const bf16x8*)&qkv[rowQ + 32 + s16 * 8];
    const int qb = qrow0 + s16 * 4;
    const float* mrow = mask + ((long)b * 1024 + qb) * 1024;

    auto loadM = [&](int k0, float (&m)[4][4]) {
#pragma unroll
      for (int g = 0; g < 4; ++g)
#pragma unroll
        for (int r = 0; r < 4; ++r)
          m[g][r] = mrow[(long)r * 1024 + k0 + g * 16 + col];
    };

    float m_run[4], l_run[4];
    f32x4 o_acc[4];
#pragma unroll
    for (int r = 0; r < 4; ++r) { m_run[r] = -INFINITY; l_run[r] = 0.f; }
#pragma unroll
    for (int go = 0; go < 4; ++go) o_acc[go] = f32x4{0.f, 0.f, 0.f, 0.f};

    bf16x8 tv0, tv1;
    stageK(0, 0);
    loadV(0, tv0, tv1);
    storeV(0, tv0, tv1);
    float msk[4][4];
    loadM(0, msk);
    __syncthreads();

#pragma unroll 1
    for (int kt = 0; kt <= qt; ++kt) {
      const int cur = kt & 1;
      const bool more = kt < qt;
      const int k0 = kt * 64;
      float mnx[4][4];
      if (more) {
        stageK(cur ^ 1, k0 + 64);
        loadV(k0 + 64, tv0, tv1);
        loadM(k0 + 64, mnx);
      }

      f32x4 sf[4];
      __builtin_amdgcn_s_setprio(1);
#pragma unroll
      for (int g = 0; g < 4; ++g) {
        const int rbyte = (g * 16 + col) * 128;
        bf16x8 bk0 = *(const bf16x8*)((char*)&Kl[cur][0] + rbyte + sw0);
        bf16x8 bk1 = *(const bf16x8*)((char*)&Kl[cur][0] + rbyte + sw1);
        f32x4 z = f32x4{0.f, 0.f, 0.f, 0.f};
        z = __builtin_amdgcn_mfma_f32_16x16x32_bf16(aq0, bk0, z, 0, 0, 0);
        z = __builtin_amdgcn_mfma_f32_16x16x32_bf16(aq1, bk1, z, 0, 0, 0);
        sf[g] = z;
      }
      __builtin_amdgcn_s_setprio(0);

      const bool diag = (kt == qt);
      float sv[4][4];
#pragma unroll
      for (int g = 0; g < 4; ++g)
#pragma unroll
        for (int r = 0; r < 4; ++r) {
          float s = sf[g][r] * 0.125f + msk[g][r];
          if (diag && (k0 + g * 16 + col) > (qb + r)) s = -INFINITY;
          sv[g][r] = s;
        }
#pragma unroll
      for (int r = 0; r < 4; ++r) {
        float mx = fmaxf(fmaxf(sv[0][r], sv[1][r]), fmaxf(sv[2][r], sv[3][r]));
#pragma unroll
        for (int o = 8; o; o >>= 1) mx = fmaxf(mx, __shfl_xor(mx, o));
        const float m_new = fmaxf(m_run[r], mx);
        const float f = __expf(m_run[r] - m_new);
        m_run[r] = m_new;
        float sum = 0.f;
#pragma unroll
        for (int g = 0; g < 4; ++g) {
          const float p = __expf(sv[g][r] - m_new);
          sv[g][r] = p;
          sum += p;
        }
#pragma unroll
        for (int o = 8; o; o >>= 1) sum += __shfl_xor(sum, o);
        l_run[r] = l_run[r] * f + sum;
#pragma unroll
        for (int go = 0; go < 4; ++go) o_acc[go][r] *= f;
      }

#pragma unroll
      for (int g = 0; g < 4; ++g) {
        const int ks = 2 * g + (col >> 3);
#pragma unroll
        for (int r = 0; r < 4; ++r) {
          const int qr = s16 * 4 + r;
          *(bf16_t*)(plw + qr * 128 + ((ks ^ (qr & 7)) << 4) + l7 * 2) = (bf16_t)sv[g][r];
        }
      }
      const bf16x8 pa0 = *(const bf16x8*)(plw + col * 128 + sw0);
      const bf16x8 pa1 = *(const bf16x8*)(plw + col * 128 + sw1);
      __builtin_amdgcn_s_setprio(1);
#pragma unroll
      for (int go = 0; go < 4; ++go) {
        const int dbyte = (go * 16 + col) * 128;
        bf16x8 bv0 = *(const bf16x8*)((char*)&Vt[cur][0] + dbyte + sw0);
        bf16x8 bv1 = *(const bf16x8*)((char*)&Vt[cur][0] + dbyte + sw1);
        o_acc[go] = __builtin_amdgcn_mfma_f32_16x16x32_bf16(pa0, bv0, o_acc[go], 0, 0, 0);
        o_acc[go] = __builtin_amdgcn_mfma_f32_16x16x32_bf16(pa1, bv1, o_acc[go], 0, 0, 0);
      }
      __builtin_amdgcn_s_setprio(0);

      if (more) {
        storeV(cur ^ 1, tv0, tv1);
#pragma unroll
        for (int g = 0; g < 4; ++g)
#pragma unroll
          for (int r = 0; r < 4; ++r) msk[g][r] = mnx[g][r];
      }
      __syncthreads();
    }

    float inv[4];
#pragma unroll
    for (int r = 0; r < 4; ++r) inv[r] = 1.f / l_run[r];
#pragma unroll
    for (int go = 0; go < 4; ++go)
#pragma unroll
      for (int r = 0; r < 4; ++r)
        out[(long)(b * 1024 + qb + r) * 768 + h * 64 + go * 16 + col] =
            (bf16_t)(o_acc[go][r] * inv[r]);
  }
}

// ---------------- host
extern "C" void kernel_launch(void* const* d_in, const int* in_sizes, int n_in,
                              void* d_out, int out_size, void* d_ws, size_t ws_size,
                              hipStream_t stream) {
  const int*   x_ids = (const int*)d_in[0];
  const float* mask  = (const float*)d_in[1];
  const float* wte   = (const float*)d_in[2];
  const float* wpe   = (const float*)d_in[3];
  const float* ln1_g = (const float*)d_in[4];
  const float* ln1_b = (const float*)d_in[5];
  const float* qkv_w = (const float*)d_in[6];
  const float* qkv_b = (const float*)d_in[7];
  const float* ao_w  = (const float*)d_in[8];
  const float* ao_b  = (const float*)d_in[9];
  const float* ln2_g = (const float*)d_in[10];
  const float* ln2_b = (const float*)d_in[11];
  const float* fc_w  = (const float*)d_in[12];
  const float* fc_b  = (const float*)d_in[13];
  const float* op_w  = (const float*)d_in[14];
  const float* op_b  = (const float*)d_in[15];
  const float* lnf_g = (const float*)d_in[16];
  const float* lnf_b = (const float*)d_in[17];

  char* ws = (char*)d_ws;
  size_t off = 0;
  auto alloc = [&](size_t bytes) {
    char* p = ws + off;
    off += (bytes + 255) & ~(size_t)255;
    return p;
  };
  bf16_t* wqT = (bf16_t*)alloc(6ull * 2304 * 768 * 2);
  bf16_t* waT = (bf16_t*)alloc(6ull * 768 * 768 * 2);
  bf16_t* wfT = (bf16_t*)alloc(6ull * 3072 * 768 * 2);
  bf16_t* woT = (bf16_t*)alloc(6ull * 768 * 3072 * 2);
  bf16_t* h   = (bf16_t*)alloc(8192ull * 768 * 2);     // residual stream, bf16
  bf16_t* xb  = (bf16_t*)alloc(8192ull * 768 * 2);
  bf16_t* qkv = (bf16_t*)alloc(8192ull * 2304 * 2);
  bf16_t* abf = (bf16_t*)alloc(8192ull * 768 * 2);
  bf16_t* fb  = (bf16_t*)alloc(8192ull * 3072 * 2);
  if (off > ws_size) return;

  // batched transposes: one launch per weight class (z = layer)
  transpose_cast<<<dim3(768 / 32, 2304 / 32, 6), 256, 0, stream>>>(qkv_w, wqT, 768, 2304);
  transpose_cast<<<dim3(768 / 32, 768 / 32, 6), 256, 0, stream>>>(ao_w, waT, 768, 768);
  transpose_cast<<<dim3(768 / 32, 3072 / 32, 6), 256, 0, stream>>>(fc_w, wfT, 768, 3072);
  transpose_cast<<<dim3(3072 / 32, 768 / 32, 6), 256, 0, stream>>>(op_w, woT, 3072, 768);

  embed_kernel<<<3072, 256, 0, stream>>>(x_ids, wte, wpe, h);

  for (int l = 0; l < 6; ++l) {
    ln_kernel<true><<<2048, 256, 0, stream>>>(h, ln1_g + l * 768, ln1_b + l * 768, xb, nullptr);
    // qkv: 8192x2304 K=768 -> 256x128 tile, grid 32*18 = 576 (all-resident @3/CU)
    gemm_bw<2><<<576, 512, 0, stream>>>(xb, wqT + (long)l * 2304 * 768,
                                        qkv_b + l * 2304, qkv, 8192, 2304, 768);
    attn_kernel<<<768, 256, 0, stream>>>(qkv, mask, abf);
    // ao: 8192x768 K=768 -> BN=64 BK=128 grid 768, bf16 residual RMW
    gemm_bt<1, 64><<<768, 256, 0, stream>>>(abf, waT + (long)l * 768 * 768,
                                            ao_b + l * 768, h, 8192, 768, 768);
    ln_kernel<true><<<2048, 256, 0, stream>>>(h, ln2_g + l * 768, ln2_b + l * 768, xb, nullptr);
    // fc: 8192x3072 K=768 -> 256x128 tile, grid 32*24 = 768 (one round @3/CU)
    gemm_bw<3><<<768, 512, 0, stream>>>(xb, wfT + (long)l * 3072 * 768,
                                        fc_b + l * 3072, fb, 8192, 3072, 768);
    // op: 8192x768 K=3072 -> BN=64 BK=128 grid 768, bf16 residual RMW
    gemm_bt<1, 64><<<768, 256, 0, stream>>>(fb, woT + (long)l * 768 * 3072,
                                            op_b + l * 768, h, 8192, 768, 3072);
  }

  ln_kernel<false><<<2048, 256, 0, stream>>>(h, lnf_g, lnf_b, nullptr, (float*)d_out);
}